// Round 15
// baseline (246.608 us; speedup 1.0000x reference)
//
#include <hip/hip_runtime.h>
#include <math.h>

typedef unsigned short u16;
typedef unsigned int u32;
typedef __attribute__((ext_vector_type(4))) float f32x4;
typedef __attribute__((ext_vector_type(8))) short short8;
typedef __attribute__((ext_vector_type(4))) unsigned short u16x4;

#define B_DIM 2
#define L_SEQ 4096
#define E_DIM 512
#define NH 8
#define HD 64
#define HID_DIM 2048
#define BL (B_DIM * L_SEQ)

__device__ __forceinline__ float bf2f(u16 u) {
    union { u32 i; float f; } v; v.i = ((u32)u) << 16; return v.f;
}
__device__ __forceinline__ u16 f2bf(float f) {
    union { float f; u32 i; } v; v.f = f;
    u32 r = v.i + 0x7fffu + ((v.i >> 16) & 1u);
    return (u16)(r >> 16);
}
__device__ __forceinline__ float gelu_f(float v) {
    float y = fminf(0.7978845608f * (v + 0.044715f * v * v * v), 15.f);
    float t = __expf(2.f * y);
    return v * (t / (t + 1.f));
}

#define GLOAD_LDS16(gp, lp) __builtin_amdgcn_global_load_lds( \
    (const __attribute__((address_space(1))) void*)(gp),      \
    (__attribute__((address_space(3))) void*)(lp), 16, 0, 0)

template<int VM> __device__ __forceinline__ void waitvm() {
    asm volatile("s_waitcnt vmcnt(%0)" :: "n"(VM) : "memory");
}
#define SBAR() __builtin_amdgcn_sched_barrier(0)

// ---------------- weight convert + transpose via LDS tiles: f32 [Kd][Nd] -> bf16 [Nd][Kd] ----
__global__ __launch_bounds__(256) void wconv_t(const float* __restrict__ in,
                                               u16* __restrict__ out, int Kd, int Nd) {
    __shared__ u16 t[64][72];
    const int k0 = blockIdx.y * 64, n0 = blockIdx.x * 64;
    const int tid = threadIdx.x;
    const int col4 = tid & 15;
    const int rowb = tid >> 4;
#pragma unroll
    for (int i = 0; i < 4; ++i) {
        const int k = rowb + i * 16;
        const float4 v = *(const float4*)(in + (size_t)(k0 + k) * Nd + n0 + col4 * 4);
        t[col4 * 4 + 0][k] = f2bf(v.x);
        t[col4 * 4 + 1][k] = f2bf(v.y);
        t[col4 * 4 + 2][k] = f2bf(v.z);
        t[col4 * 4 + 3][k] = f2bf(v.w);
    }
    __syncthreads();
    const int n = tid >> 2, ch = tid & 3;
    u16* dst = out + (size_t)(n0 + n) * Kd + k0 + ch * 16;
    *(short8*)(dst) = *(const short8*)&t[n][ch * 16];
    *(short8*)(dst + 8) = *(const short8*)&t[n][ch * 16 + 8];
}

// ---------------- LayerNorm: f32 [rows][512] -> bf16 [rows][512], wave per row ----------------
__global__ __launch_bounds__(256) void ln_kernel(const float* __restrict__ x,
                                                 const float* __restrict__ g,
                                                 const float* __restrict__ b,
                                                 u16* __restrict__ out) {
    const int row = blockIdx.x * 4 + (threadIdx.x >> 6);
    const int lane = threadIdx.x & 63;
    const float4* xr = (const float4*)(x + (size_t)row * E_DIM);
    const float4 v0 = xr[lane];
    const float4 v1 = xr[lane + 64];
    float s  = v0.x + v0.y + v0.z + v0.w + v1.x + v1.y + v1.z + v1.w;
    float s2 = v0.x*v0.x + v0.y*v0.y + v0.z*v0.z + v0.w*v0.w
             + v1.x*v1.x + v1.y*v1.y + v1.z*v1.z + v1.w*v1.w;
#pragma unroll
    for (int off = 32; off > 0; off >>= 1) {
        s  += __shfl_xor(s, off);
        s2 += __shfl_xor(s2, off);
    }
    const float mu = s * (1.f / E_DIM);
    const float rs = rsqrtf(s2 * (1.f / E_DIM) - mu * mu + 1e-5f);
    const float4 g0 = ((const float4*)g)[lane], g1 = ((const float4*)g)[lane + 64];
    const float4 b0 = ((const float4*)b)[lane], b1 = ((const float4*)b)[lane + 64];
    u16x4 o0, o1;
    o0.x = f2bf((v0.x - mu) * rs * g0.x + b0.x);
    o0.y = f2bf((v0.y - mu) * rs * g0.y + b0.y);
    o0.z = f2bf((v0.z - mu) * rs * g0.z + b0.z);
    o0.w = f2bf((v0.w - mu) * rs * g0.w + b0.w);
    o1.x = f2bf((v1.x - mu) * rs * g1.x + b1.x);
    o1.y = f2bf((v1.y - mu) * rs * g1.y + b1.y);
    o1.z = f2bf((v1.z - mu) * rs * g1.z + b1.z);
    o1.w = f2bf((v1.w - mu) * rs * g1.w + b1.w);
    u16x4* orow = (u16x4*)(out + (size_t)row * E_DIM);
    orow[lane] = o0;
    orow[lane + 64] = o1;
}

// ---------------- GEMM, reg-B variant: A via LDS (global_load_lds), B direct global->VGPR ----
// r14 fix: vmcnt wait levels are functions of NR (B-loads per step). r12/r13 hardcoded the
// NR=4 values (6/10/9/8); for NR=2 (out-proj) the steady wait must be 2NR+2=6, not 10 --
// waitvm<10> reached back past A(t), racing the out-proj and corrupting downstream (absmax
// 0.34 both rounds). Waits: prologue NR+2, steady 2NR+2, tails 2NR+1 / 2NR.
// Issue order pinned with sched_barrier(0) so the counts are well-defined (r13).
template<int K_T, int BM_T, int BN_T, bool RES, bool GELU, bool OUTBF>
__global__ __launch_bounds__(512) void gemm_rb(const u16* __restrict__ A,
                                               const u16* __restrict__ Bt,
                                               const float* __restrict__ bias,
                                               const float* __restrict__ res,
                                               void* __restrict__ Cp,
                                               int M, int N, int nbx) {
    constexpr int K = K_T;
    constexpr int NT = K / 32;                 // K-steps (>= 4)
    constexpr int MR = BM_T / 32;              // A frags per wave (2 or 4)
    constexpr int NR = BN_T / 64;              // B frags per wave (2 or 4)
    constexpr int ASTW = BM_T / 16;            // waves that stage A (4 or 8)
    constexpr int AU = BM_T * 32;              // u16 per A subtile
    constexpr int W_PRO = NR + 2;              // ops after A(0) at first wait
    constexpr int W_STD = 2 * NR + 2;          // ops after A(t), steady
    constexpr int W_T1  = 2 * NR + 1;          // t = NT-2
    constexpr int W_T2  = 2 * NR;              // t = NT-1
    __shared__ u16 sb[3 * AU];
    const int tid = threadIdx.x;
    const int wave = tid >> 6, lane = tid & 63;
    const int wr = wave >> 2, wc = wave & 3;   // 2 x 4 wave grid

    const int xcd = blockIdx.x & 7;
    const int q = blockIdx.x >> 3;
    const int bx = q % nbx;
    const int by = (q / nbx) * 8 + xcd;
    const int bm = by * BM_T, bn = bx * BN_T;

    f32x4 acc[MR][NR];
#pragma unroll
    for (int m = 0; m < MR; ++m)
#pragma unroll
        for (int n = 0; n < NR; ++n) acc[m][n] = 0.f;

    const int sr = lane & 15;
    const int sg = lane >> 4;
    const u16* gA = A + (size_t)(bm + wave * 16 + sr) * K + sg * 8;
    const u16* gBf = Bt + (size_t)(bn + wc * (NR * 16) + sr) * K + sg * 8;

    auto stageA = [&](int buf, int t) {
        if (wave < ASTW)
            GLOAD_LDS16(gA + t * 32, sb + buf * AU + wave * 512);
    };

    short8 breg[NR];
    auto loadB = [&](int t) {
#pragma unroll
        for (int n = 0; n < NR; ++n)
            breg[n] = *(const short8*)(gBf + (size_t)n * 16 * K + t * 32);
    };

    auto compute = [&](int buf) {
        const u16* src = sb + buf * AU;
        short8 af[MR];
#pragma unroll
        for (int m = 0; m < MR; ++m)
            af[m] = *(const short8*)&src[(wr * MR + m) * 512 + lane * 8];
        __builtin_amdgcn_s_setprio(1);
#pragma unroll
        for (int m = 0; m < MR; ++m)
#pragma unroll
            for (int n = 0; n < NR; ++n)
                acc[m][n] = __builtin_amdgcn_mfma_f32_16x16x32_bf16(af[m], breg[n], acc[m][n], 0, 0, 0);
        __builtin_amdgcn_s_setprio(0);
    };

    // prologue -- pinned issue order: A0, A1, B0xNR, A2
    stageA(0, 0);  SBAR();
    stageA(1, 1);  SBAR();
    loadB(0);      SBAR();
    stageA(2, 2);  SBAR();
    waitvm<W_PRO>();
    __builtin_amdgcn_s_barrier();
    SBAR();
    compute(0);
    SBAR();
    __builtin_amdgcn_s_barrier();
    int sbuf = 0, cbuf = 1;                     // tile t -> buf t%3
    for (int t = 1; t <= NT - 3; ++t) {
        loadB(t);                      SBAR();  // pinned: B(t)xNR then A(t+2)
        stageA(sbuf, t + 2);           SBAR();
        sbuf = (sbuf == 2) ? 0 : sbuf + 1;
        waitvm<W_STD>();
        __builtin_amdgcn_s_barrier();
        SBAR();
        compute(cbuf);
        SBAR();
        __builtin_amdgcn_s_barrier();
        cbuf = (cbuf == 2) ? 0 : cbuf + 1;
    }
    // t = NT-2 (no stage)
    loadB(NT - 2);  SBAR();
    waitvm<W_T1>();
    __builtin_amdgcn_s_barrier();
    SBAR();
    compute(cbuf);
    SBAR();
    __builtin_amdgcn_s_barrier();
    cbuf = (cbuf == 2) ? 0 : cbuf + 1;
    // t = NT-1
    loadB(NT - 1);  SBAR();
    waitvm<W_T2>();
    __builtin_amdgcn_s_barrier();
    SBAR();
    compute(cbuf);

    const int ccol = lane & 15;
    const int crow = (lane >> 4) * 4;
#pragma unroll
    for (int n = 0; n < NR; ++n) {
        const int gc = bn + wc * (NR * 16) + n * 16 + ccol;
        const float bi = bias[gc];
#pragma unroll
        for (int m = 0; m < MR; ++m) {
            const int gr0 = bm + wr * (MR * 16) + m * 16 + crow;
#pragma unroll
            for (int j = 0; j < 4; ++j) {
                float v = acc[m][n][j] + bi;
                if (GELU) v = gelu_f(v);
                const size_t idx = (size_t)(gr0 + j) * N + gc;
                if (RES) v += res[idx];
                if (OUTBF) ((u16*)Cp)[idx] = f2bf(v);
                else       ((float*)Cp)[idx] = v;
            }
        }
    }
}

// ---------------- dilated attention via parity split -> dense sliding-window flash attn ------
__global__ __launch_bounds__(256) void attn_mfma(const u16* __restrict__ qkv,
                                                 u16* __restrict__ o) {
    __shared__ u16 K_lds[32 * 64];
    __shared__ u16 V_lds[32 * 64];
    const int tid = threadIdx.x;
    const int w = tid >> 6, lane = tid & 63;
    const int g = lane >> 4, q = lane & 15;
    const int qt = blockIdx.x, bph = blockIdx.y;
    const int b = bph >> 4, p = (bph >> 3) & 1, h = bph & 7;
    const int q0 = qt * 64;

    const size_t rowstride = 3 * E_DIM;
    const u16* qbase = qkv + (size_t)b * L_SEQ * rowstride + h * HD;

    const int qmin = q0 + w * 16, qmax = qmin + 15;
    const int qs_lane = qmin + q;
    const int qi = 2 * qs_lane + p;

    short8 qfrag[2];
    qfrag[0] = *(const short8*)(qbase + (size_t)qi * rowstride + g * 8);
    qfrag[1] = *(const short8*)(qbase + (size_t)qi * rowstride + 32 + g * 8);

    f32x4 oacc[4];
#pragma unroll
    for (int dt = 0; dt < 4; ++dt) oacc[dt] = 0.f;
    float m = -1e30f, l = 0.f;

    for (int s = 0; s < 6; ++s) {
        const int ks0 = q0 - 128 + 32 * s;
        if (ks0 >= 0) {
            const int r = 8 * w + (lane >> 3);
            const int gr = lane & 7;
            const size_t krow = (size_t)(2 * (ks0 + r) + p) * rowstride;
            const u16* ksrc = qbase + krow + E_DIM + 8 * (gr ^ (r & 7));
            const u16* vsrc = qbase + krow + 2 * E_DIM + 8 * gr;
            GLOAD_LDS16(ksrc, &K_lds[w * 512]);
            GLOAD_LDS16(vsrc, &V_lds[w * 512]);
        }
        __syncthreads();
        const bool active = (ks0 >= 0) && (ks0 <= qmax) && (ks0 + 31 >= qmin - 128);
        if (active) {
            f32x4 st[2];
            st[0] = 0.f; st[1] = 0.f;
#pragma unroll
            for (int t = 0; t < 2; ++t) {
#pragma unroll
                for (int c = 0; c < 2; ++c) {
                    const int kk = t * 16 + q;
                    const int gs = (c * 4 + g) ^ (kk & 7);
                    short8 kf = *(const short8*)&K_lds[kk * 64 + gs * 8];
                    st[t] = __builtin_amdgcn_mfma_f32_16x16x32_bf16(kf, qfrag[c], st[t], 0, 0, 0);
                }
            }
            float sv[2][4];
            float bm = -3.0e38f;
#pragma unroll
            for (int t = 0; t < 2; ++t)
#pragma unroll
                for (int j = 0; j < 4; ++j) {
                    const int kk = ks0 + t * 16 + 4 * g + j;
                    float x = st[t][j] * 0.125f;
                    const bool ok = (kk <= qs_lane) && (qs_lane - kk <= 128);
                    x = ok ? x : -3.0e38f;
                    sv[t][j] = x;
                    bm = fmaxf(bm, x);
                }
            bm = fmaxf(bm, __shfl_xor(bm, 16));
            bm = fmaxf(bm, __shfl_xor(bm, 32));
            const float mn = fmaxf(m, bm);
            const float sc = __expf(m - mn);
            m = mn;
            float rs = 0.f;
            u32 pk[2][2];
#pragma unroll
            for (int t = 0; t < 2; ++t) {
                const float e0 = __expf(sv[t][0] - mn), e1 = __expf(sv[t][1] - mn);
                const float e2 = __expf(sv[t][2] - mn), e3 = __expf(sv[t][3] - mn);
                rs += (e0 + e1) + (e2 + e3);
                pk[t][0] = (u32)f2bf(e0) | ((u32)f2bf(e1) << 16);
                pk[t][1] = (u32)f2bf(e2) | ((u32)f2bf(e3) << 16);
            }
            rs += __shfl_xor(rs, 16);
            rs += __shfl_xor(rs, 32);
            l = l * sc + rs;
#pragma unroll
            for (int dt = 0; dt < 4; ++dt) oacc[dt] *= sc;
            union { u32 w4[4]; short8 s8; } bfr;
#pragma unroll
            for (int r = 0; r < 4; ++r) {
                const int src = (((g << 1) + (r >> 1)) & 3) * 16 + q;
                const int w0 = __shfl((int)pk[0][r & 1], src);
                const int w1 = __shfl((int)pk[1][r & 1], src);
                bfr.w4[r] = (g & 2) ? (u32)w1 : (u32)w0;
            }
#pragma unroll
            for (int dt = 0; dt < 4; ++dt) {
                union { u16 h8[8]; short8 s8; } vf;
#pragma unroll
                for (int e = 0; e < 8; ++e)
                    vf.h8[e] = V_lds[(8 * g + e) * 64 + dt * 16 + q];
                oacc[dt] = __builtin_amdgcn_mfma_f32_16x16x32_bf16(vf.s8, bfr.s8, oacc[dt], 0, 0, 0);
            }
        }
        __syncthreads();
    }
    const float inv = 1.f / l;
    u16* obase = o + ((size_t)b * L_SEQ + (size_t)qi) * E_DIM + h * HD;
#pragma unroll
    for (int dt = 0; dt < 4; ++dt) {
        u16x4 pkd;
        pkd.x = f2bf(oacc[dt][0] * inv);
        pkd.y = f2bf(oacc[dt][1] * inv);
        pkd.z = f2bf(oacc[dt][2] * inv);
        pkd.w = f2bf(oacc[dt][3] * inv);
        *(u16x4*)(obase + dt * 16 + 4 * g) = pkd;
    }
}

// --------------------------------------------------------------------------------------------
extern "C" void kernel_launch(void* const* d_in, const int* in_sizes, int n_in,
                              void* d_out, int out_size, void* d_ws, size_t ws_size,
                              hipStream_t stream) {
    const float* x    = (const float*)d_in[0];
    const float* ln1g = (const float*)d_in[1];
    const float* ln1b = (const float*)d_in[2];
    const float* qkvw = (const float*)d_in[3];
    const float* qkvb = (const float*)d_in[4];
    const float* outw = (const float*)d_in[5];
    const float* outb = (const float*)d_in[6];
    const float* ln2g = (const float*)d_in[7];
    const float* ln2b = (const float*)d_in[8];
    const float* w1   = (const float*)d_in[9];
    const float* b1   = (const float*)d_in[10];
    const float* w2   = (const float*)d_in[11];
    const float* b2   = (const float*)d_in[12];
    float* outp = (float*)d_out;

    char* ws = (char*)d_ws;
    size_t off = 0;
    auto alloc = [&](size_t bytes) {
        void* p = ws + off;
        off += (bytes + 255) & ~(size_t)255;
        return p;
    };
    u16*   hbuf  = (u16*)  alloc((size_t)BL * E_DIM * 2);
    u16*   qkvB  = (u16*)  alloc((size_t)BL * 3 * E_DIM * 2);
    u16*   obuf  = (u16*)  alloc((size_t)BL * E_DIM * 2);
    float* x2    = (float*)alloc((size_t)BL * E_DIM * 4);
    u16*   h2    = (u16*)  alloc((size_t)BL * E_DIM * 2);
    u16*   g1    = (u16*)  alloc((size_t)BL * HID_DIM * 2);
    u16*   wqkvT = (u16*)  alloc((size_t)3 * E_DIM * E_DIM * 2);
    u16*   woutT = (u16*)  alloc((size_t)E_DIM * E_DIM * 2);
    u16*   w1T   = (u16*)  alloc((size_t)HID_DIM * E_DIM * 2);
    u16*   w2T   = (u16*)  alloc((size_t)E_DIM * HID_DIM * 2);

    wconv_t<<<dim3((3 * E_DIM) / 64, E_DIM / 64), 256, 0, stream>>>(qkvw, wqkvT, E_DIM, 3 * E_DIM);
    wconv_t<<<dim3(E_DIM / 64, E_DIM / 64), 256, 0, stream>>>(outw, woutT, E_DIM, E_DIM);
    wconv_t<<<dim3(HID_DIM / 64, E_DIM / 64), 256, 0, stream>>>(w1, w1T, E_DIM, HID_DIM);
    wconv_t<<<dim3(E_DIM / 64, HID_DIM / 64), 256, 0, stream>>>(w2, w2T, HID_DIM, E_DIM);

    ln_kernel<<<BL / 4, 256, 0, stream>>>(x, ln1g, ln1b, hbuf);
    gemm_rb<E_DIM, 128, 256, false, false, true><<<(BL / 128) * 6, 512, 0, stream>>>(
        hbuf, wqkvT, qkvb, nullptr, qkvB, BL, 3 * E_DIM, 6);
    attn_mfma<<<dim3(32, 32), 256, 0, stream>>>(qkvB, obuf);
    gemm_rb<E_DIM, 64, 128, true, false, false><<<(BL / 64) * 4, 512, 0, stream>>>(
        obuf, woutT, outb, x, x2, BL, E_DIM, 4);
    ln_kernel<<<BL / 4, 256, 0, stream>>>(x2, ln2g, ln2b, h2);
    gemm_rb<E_DIM, 128, 256, false, true, true><<<(BL / 128) * 8, 512, 0, stream>>>(
        h2, w1T, b1, nullptr, g1, BL, HID_DIM, 8);
    gemm_rb<HID_DIM, 64, 256, true, false, false><<<(BL / 64) * 2, 512, 0, stream>>>(
        g1, w2T, b2, x2, outp, BL, E_DIM, 2);
}

// Round 16
// 134.437 us; speedup vs baseline: 1.8344x; 1.8344x over previous
//
#include <hip/hip_runtime.h>
#include <math.h>

typedef unsigned char u8;
typedef unsigned short u16;
typedef unsigned int u32;
typedef __attribute__((ext_vector_type(4))) float f32x4;
typedef __attribute__((ext_vector_type(8))) short short8;

#define B_DIM 2
#define L_SEQ 4096
#define E_DIM 512
#define NH 8
#define HD 64
#define HID_DIM 2048
#define BL (B_DIM * L_SEQ)

__device__ __forceinline__ float bf2f(u16 u) {
    union { u32 i; float f; } v; v.i = ((u32)u) << 16; return v.f;
}
__device__ __forceinline__ u16 f2bf(float f) {
    union { float f; u32 i; } v; v.f = f;
    u32 r = v.i + 0x7fffu + ((v.i >> 16) & 1u);
    return (u16)(r >> 16);
}
__device__ __forceinline__ u32 pk2_fp8(float a, float b) {
    return (u32)__builtin_amdgcn_cvt_pk_fp8_f32(a, b, 0, false); // byte0=fp8(a), byte1=fp8(b)
}
__device__ __forceinline__ u8 f2fp8(float a) { return (u8)(pk2_fp8(a, a) & 0xffu); }
__device__ __forceinline__ float gelu_f(float v) {
    float y = fminf(0.7978845608f * (v + 0.044715f * v * v * v), 15.f);
    float t = __expf(2.f * y);
    return v * (t / (t + 1.f));
}

#define GLOAD_LDS16(gp, lp) __builtin_amdgcn_global_load_lds( \
    (const __attribute__((address_space(1))) void*)(gp),      \
    (__attribute__((address_space(3))) void*)(lp), 16, 0, 0)

template<int VM> __device__ __forceinline__ void waitvm() {
    asm volatile("s_waitcnt vmcnt(%0)" :: "n"(VM) : "memory");
}

// -------- weight convert+transpose: f32 [Kd][Nd] -> fp8 e4m3 [Nd][Kd], PRESCALED x32 --------
// (w ~ N(0,0.02) is subnormal in e4m3 -> ~20% rel err; x32 -> N(0,0.64), ~2%. Epilogue /32.)
__global__ __launch_bounds__(256) void wconv_f8(const float* __restrict__ in,
                                                u8* __restrict__ out, int Kd, int Nd) {
    __shared__ u8 t[64][96];           // row stride 96 keeps 16B-aligned chunks
    const int k0 = blockIdx.y * 64, n0 = blockIdx.x * 64;
    const int tid = threadIdx.x;
    const int col4 = tid & 15, rowb = tid >> 4;
#pragma unroll
    for (int i = 0; i < 4; ++i) {
        const int k = rowb + i * 16;
        const float4 v = *(const float4*)(in + (size_t)(k0 + k) * Nd + n0 + col4 * 4);
        const u32 p01 = pk2_fp8(v.x * 32.f, v.y * 32.f);
        const u32 p23 = pk2_fp8(v.z * 32.f, v.w * 32.f);
        t[col4 * 4 + 0][k] = (u8)(p01 & 0xff);
        t[col4 * 4 + 1][k] = (u8)((p01 >> 8) & 0xff);
        t[col4 * 4 + 2][k] = (u8)(p23 & 0xff);
        t[col4 * 4 + 3][k] = (u8)((p23 >> 8) & 0xff);
    }
    __syncthreads();
    const int n = tid >> 2, ch = tid & 3;
    u8* dst = out + (size_t)(n0 + n) * Kd + k0 + ch * 16;
    *(short8*)dst = *(const short8*)&t[n][ch * 16];
}

// ---------------- LayerNorm: f32 [rows][512] -> fp8 [rows][512], wave per row ----------------
__global__ __launch_bounds__(256) void ln_f8(const float* __restrict__ x,
                                             const float* __restrict__ g,
                                             const float* __restrict__ b,
                                             u8* __restrict__ out) {
    const int row = blockIdx.x * 4 + (threadIdx.x >> 6);
    const int lane = threadIdx.x & 63;
    const float4* xr = (const float4*)(x + (size_t)row * E_DIM);
    const float4 v0 = xr[lane];
    const float4 v1 = xr[lane + 64];
    float s  = v0.x + v0.y + v0.z + v0.w + v1.x + v1.y + v1.z + v1.w;
    float s2 = v0.x*v0.x + v0.y*v0.y + v0.z*v0.z + v0.w*v0.w
             + v1.x*v1.x + v1.y*v1.y + v1.z*v1.z + v1.w*v1.w;
#pragma unroll
    for (int off = 32; off > 0; off >>= 1) {
        s  += __shfl_xor(s, off);
        s2 += __shfl_xor(s2, off);
    }
    const float mu = s * (1.f / E_DIM);
    const float rs = rsqrtf(s2 * (1.f / E_DIM) - mu * mu + 1e-5f);
    const float4 g0 = ((const float4*)g)[lane], g1 = ((const float4*)g)[lane + 64];
    const float4 b0 = ((const float4*)b)[lane], b1 = ((const float4*)b)[lane + 64];
    const float a0 = (v0.x - mu) * rs * g0.x + b0.x;
    const float a1 = (v0.y - mu) * rs * g0.y + b0.y;
    const float a2 = (v0.z - mu) * rs * g0.z + b0.z;
    const float a3 = (v0.w - mu) * rs * g0.w + b0.w;
    const float a4 = (v1.x - mu) * rs * g1.x + b1.x;
    const float a5 = (v1.y - mu) * rs * g1.y + b1.y;
    const float a6 = (v1.z - mu) * rs * g1.z + b1.z;
    const float a7 = (v1.w - mu) * rs * g1.w + b1.w;
    u32* orow = (u32*)(out + (size_t)row * E_DIM);
    orow[lane]      = pk2_fp8(a0, a1) | (pk2_fp8(a2, a3) << 16);
    orow[lane + 64] = pk2_fp8(a4, a5) | (pk2_fp8(a6, a7) << 16);
}

// ---------------- fp8 GEMM: C[M][N] = A[M][K](e4m3) @ Bt[N][K](e4m3, x32) ------------------
// r10-verified skeleton (8 waves 2x4, 3-buffer ring, counted vmcnt 2L/L/0), BK=64, fp8 bytes.
// LDS layout per operand: [kg = ks*2+g2][row-group(16)][row][16B]; group offset = gr*256.
// Frag read = ds_read_b64 at (ks*2+(g>>1))*KGS + gr*256 + r*16 + (g&1)*8.
// Epilogue: acc * (1/32) [weight prescale] + bias (+gelu) (+res); OUT: 0=bf16, 1=f32, 2=fp8.
template<int K_T, int BN_T, int OUT, bool RES, bool GELU>
__global__ __launch_bounds__(512) void gemm_f8(const u8* __restrict__ A,
                                               const u8* __restrict__ Bt,
                                               const float* __restrict__ bias,
                                               const float* __restrict__ res,
                                               void* __restrict__ Cp,
                                               int M, int N, int nbx) {
    constexpr int K = K_T;
    constexpr int NT = K / 64;                 // BK=64 steps (8 or 32)
    constexpr int MR = 4;                      // BM=128 fixed
    constexpr int NR = BN_T / 64;              // 4 or 2
    constexpr int GA = 8;                      // A row-groups
    constexpr int GB = BN_T / 16;              // 16 or 8
    constexpr int LB = GB / 8;                 // B loads/wave (2 or 1); A loads/wave = 1
    constexpr int L = 1 + LB;
    constexpr int AKG_S = GA * 256;            // 2048
    constexpr int BKG_S = GB * 256;
    constexpr int ABYTES = 128 * 64;           // 8KB
    constexpr int BBYTES = BN_T * 64;
    constexpr int TILE = ABYTES + BBYTES;
    __shared__ u8 sb[3 * TILE];
    const int tid = threadIdx.x;
    const int wave = tid >> 6, lane = tid & 63;
    const int wr = wave >> 2, wc = wave & 3;   // 2 x 4 wave grid

    const int xcd = blockIdx.x & 7;
    const int q = blockIdx.x >> 3;
    const int bx = q % nbx;
    const int by = (q / nbx) * 8 + xcd;
    const int bm = by * 128, bn = bx * BN_T;

    f32x4 acc[MR][NR];
#pragma unroll
    for (int m = 0; m < MR; ++m)
#pragma unroll
        for (int n = 0; n < NR; ++n) acc[m][n] = 0.f;

    const int lrow = (lane >> 4) * 16 + (lane & 15);   // row within a 4-group span

    auto stage = [&](int buf, int t) {
        u8* dst0 = sb + buf * TILE;
        {   // A: load i = wave (GA=8)
            const int kg = wave >> 1, j = wave & 1;
            const u8* src = A + (size_t)(bm + j * 64 + lrow) * K
                            + t * 64 + (kg >> 1) * 32 + (kg & 1) * 16;
            GLOAD_LDS16(src, dst0 + kg * AKG_S + j * 1024);
        }
#pragma unroll
        for (int h = 0; h < LB; ++h) {         // B: loads i = wave*LB + h
            const int i = wave * LB + h;
            const int kg = i / (GB / 4), j = i % (GB / 4);
            const u8* src = Bt + (size_t)(bn + j * 64 + lrow) * K
                            + t * 64 + (kg >> 1) * 32 + (kg & 1) * 16;
            GLOAD_LDS16(src, dst0 + ABYTES + kg * BKG_S + j * 1024);
        }
    };

    auto compute = [&](int buf) {
        const u8* base = sb + buf * TILE;
        const int g = lane >> 4, r = lane & 15;
        const int sub = g >> 1, off8 = (g & 1) * 8;
#pragma unroll
        for (int ks = 0; ks < 2; ++ks) {
            long av[MR], bv[NR];
#pragma unroll
            for (int m = 0; m < MR; ++m)
                av[m] = *(const long*)(base + (ks * 2 + sub) * AKG_S
                                       + (wr * 4 + m) * 256 + r * 16 + off8);
#pragma unroll
            for (int n = 0; n < NR; ++n)
                bv[n] = *(const long*)(base + ABYTES + (ks * 2 + sub) * BKG_S
                                       + (wc * NR + n) * 256 + r * 16 + off8);
            __builtin_amdgcn_s_setprio(1);
#pragma unroll
            for (int m = 0; m < MR; ++m)
#pragma unroll
                for (int n = 0; n < NR; ++n)
                    acc[m][n] = __builtin_amdgcn_mfma_f32_16x16x32_fp8_fp8(av[m], bv[n], acc[m][n], 0, 0, 0);
            __builtin_amdgcn_s_setprio(0);
        }
    };

    stage(0, 0);
    stage(1, 1);
    int sbuf = 2, cbuf = 0;
    for (int t = 0; t < NT - 2; ++t) {
        stage(sbuf, t + 2);
        sbuf = (sbuf == 2) ? 0 : sbuf + 1;
        waitvm<2 * L>();                       // tile t landed; t+1, t+2 in flight
        __builtin_amdgcn_s_barrier();
        compute(cbuf);
        cbuf = (cbuf == 2) ? 0 : cbuf + 1;
        __builtin_amdgcn_s_barrier();
    }
    waitvm<L>();
    __builtin_amdgcn_s_barrier();
    compute(cbuf);
    cbuf = (cbuf == 2) ? 0 : cbuf + 1;
    __builtin_amdgcn_s_barrier();
    waitvm<0>();                               // last tile: full drain (r8 lesson)
    __builtin_amdgcn_s_barrier();
    compute(cbuf);

    const int ccol = lane & 15;
    const int crow = (lane >> 4) * 4;
#pragma unroll
    for (int n = 0; n < NR; ++n) {
        const int gc = bn + wc * (NR * 16) + n * 16 + ccol;
        const float bi = bias[gc];
#pragma unroll
        for (int m = 0; m < MR; ++m) {
            const int gr0 = bm + wr * 64 + m * 16 + crow;
#pragma unroll
            for (int j = 0; j < 4; ++j) {
                float v = acc[m][n][j] * 0.03125f + bi;   // /32 weight prescale
                if (GELU) v = gelu_f(v);
                const size_t idx = (size_t)(gr0 + j) * N + gc;
                if (RES) v += res[idx];
                if (OUT == 0)      ((u16*)Cp)[idx] = f2bf(v);
                else if (OUT == 1) ((float*)Cp)[idx] = v;
                else               ((u8*)Cp)[idx] = f2fp8(v);
            }
        }
    }
}

// ---------------- dilated attention via parity split (bf16 qkv in, fp8 o out) ---------------
__global__ __launch_bounds__(256) void attn_mfma(const u16* __restrict__ qkv,
                                                 u8* __restrict__ o) {
    __shared__ u16 K_lds[32 * 64];
    __shared__ u16 V_lds[32 * 64];
    const int tid = threadIdx.x;
    const int w = tid >> 6, lane = tid & 63;
    const int g = lane >> 4, q = lane & 15;
    const int qt = blockIdx.x, bph = blockIdx.y;
    const int b = bph >> 4, p = (bph >> 3) & 1, h = bph & 7;
    const int q0 = qt * 64;

    const size_t rowstride = 3 * E_DIM;
    const u16* qbase = qkv + (size_t)b * L_SEQ * rowstride + h * HD;

    const int qmin = q0 + w * 16, qmax = qmin + 15;
    const int qs_lane = qmin + q;
    const int qi = 2 * qs_lane + p;

    short8 qfrag[2];
    qfrag[0] = *(const short8*)(qbase + (size_t)qi * rowstride + g * 8);
    qfrag[1] = *(const short8*)(qbase + (size_t)qi * rowstride + 32 + g * 8);

    f32x4 oacc[4];
#pragma unroll
    for (int dt = 0; dt < 4; ++dt) oacc[dt] = 0.f;
    float m = -1e30f, l = 0.f;

    for (int s = 0; s < 6; ++s) {
        const int ks0 = q0 - 128 + 32 * s;
        if (ks0 >= 0) {
            const int r = 8 * w + (lane >> 3);
            const int gr = lane & 7;
            const size_t krow = (size_t)(2 * (ks0 + r) + p) * rowstride;
            const u16* ksrc = qbase + krow + E_DIM + 8 * (gr ^ (r & 7));
            const u16* vsrc = qbase + krow + 2 * E_DIM + 8 * gr;
            GLOAD_LDS16(ksrc, &K_lds[w * 512]);
            GLOAD_LDS16(vsrc, &V_lds[w * 512]);
        }
        __syncthreads();
        const bool active = (ks0 >= 0) && (ks0 <= qmax) && (ks0 + 31 >= qmin - 128);
        if (active) {
            f32x4 st[2];
            st[0] = 0.f; st[1] = 0.f;
#pragma unroll
            for (int t = 0; t < 2; ++t) {
#pragma unroll
                for (int c = 0; c < 2; ++c) {
                    const int kk = t * 16 + q;
                    const int gs = (c * 4 + g) ^ (kk & 7);
                    short8 kf = *(const short8*)&K_lds[kk * 64 + gs * 8];
                    st[t] = __builtin_amdgcn_mfma_f32_16x16x32_bf16(kf, qfrag[c], st[t], 0, 0, 0);
                }
            }
            float sv[2][4];
            float bm = -3.0e38f;
#pragma unroll
            for (int t = 0; t < 2; ++t)
#pragma unroll
                for (int j = 0; j < 4; ++j) {
                    const int kk = ks0 + t * 16 + 4 * g + j;
                    float x = st[t][j] * 0.125f;
                    const bool ok = (kk <= qs_lane) && (qs_lane - kk <= 128);
                    x = ok ? x : -3.0e38f;
                    sv[t][j] = x;
                    bm = fmaxf(bm, x);
                }
            bm = fmaxf(bm, __shfl_xor(bm, 16));
            bm = fmaxf(bm, __shfl_xor(bm, 32));
            const float mn = fmaxf(m, bm);
            const float sc = __expf(m - mn);
            m = mn;
            float rs = 0.f;
            u32 pk[2][2];
#pragma unroll
            for (int t = 0; t < 2; ++t) {
                const float e0 = __expf(sv[t][0] - mn), e1 = __expf(sv[t][1] - mn);
                const float e2 = __expf(sv[t][2] - mn), e3 = __expf(sv[t][3] - mn);
                rs += (e0 + e1) + (e2 + e3);
                pk[t][0] = (u32)f2bf(e0) | ((u32)f2bf(e1) << 16);
                pk[t][1] = (u32)f2bf(e2) | ((u32)f2bf(e3) << 16);
            }
            rs += __shfl_xor(rs, 16);
            rs += __shfl_xor(rs, 32);
            l = l * sc + rs;
#pragma unroll
            for (int dt = 0; dt < 4; ++dt) oacc[dt] *= sc;
            union { u32 w4[4]; short8 s8; } bfr;
#pragma unroll
            for (int r = 0; r < 4; ++r) {
                const int src = (((g << 1) + (r >> 1)) & 3) * 16 + q;
                const int w0 = __shfl((int)pk[0][r & 1], src);
                const int w1 = __shfl((int)pk[1][r & 1], src);
                bfr.w4[r] = (g & 2) ? (u32)w1 : (u32)w0;
            }
#pragma unroll
            for (int dt = 0; dt < 4; ++dt) {
                union { u16 h8[8]; short8 s8; } vf;
#pragma unroll
                for (int e = 0; e < 8; ++e)
                    vf.h8[e] = V_lds[(8 * g + e) * 64 + dt * 16 + q];
                oacc[dt] = __builtin_amdgcn_mfma_f32_16x16x32_bf16(vf.s8, bfr.s8, oacc[dt], 0, 0, 0);
            }
        }
        __syncthreads();
    }
    const float inv = 1.f / l;
    u8* obase = o + ((size_t)(b * L_SEQ) + (size_t)qi) * E_DIM + h * HD;
#pragma unroll
    for (int dt = 0; dt < 4; ++dt) {
        const u32 pw = pk2_fp8(oacc[dt][0] * inv, oacc[dt][1] * inv)
                     | (pk2_fp8(oacc[dt][2] * inv, oacc[dt][3] * inv) << 16);
        *(u32*)(obase + dt * 16 + 4 * g) = pw;
    }
}

// --------------------------------------------------------------------------------------------
extern "C" void kernel_launch(void* const* d_in, const int* in_sizes, int n_in,
                              void* d_out, int out_size, void* d_ws, size_t ws_size,
                              hipStream_t stream) {
    const float* x    = (const float*)d_in[0];
    const float* ln1g = (const float*)d_in[1];
    const float* ln1b = (const float*)d_in[2];
    const float* qkvw = (const float*)d_in[3];
    const float* qkvb = (const float*)d_in[4];
    const float* outw = (const float*)d_in[5];
    const float* outb = (const float*)d_in[6];
    const float* ln2g = (const float*)d_in[7];
    const float* ln2b = (const float*)d_in[8];
    const float* w1   = (const float*)d_in[9];
    const float* b1   = (const float*)d_in[10];
    const float* w2   = (const float*)d_in[11];
    const float* b2   = (const float*)d_in[12];
    float* outp = (float*)d_out;

    char* ws = (char*)d_ws;
    size_t off = 0;
    auto alloc = [&](size_t bytes) {
        void* p = ws + off;
        off += (bytes + 255) & ~(size_t)255;
        return p;
    };
    u8*    hbuf  = (u8*)   alloc((size_t)BL * E_DIM);
    u16*   qkvB  = (u16*)  alloc((size_t)BL * 3 * E_DIM * 2);
    u8*    obuf  = (u8*)   alloc((size_t)BL * E_DIM);
    float* x2    = (float*)alloc((size_t)BL * E_DIM * 4);
    u8*    h2    = (u8*)   alloc((size_t)BL * E_DIM);
    u8*    g1    = (u8*)   alloc((size_t)BL * HID_DIM);
    u8*    wqkvT = (u8*)   alloc((size_t)3 * E_DIM * E_DIM);
    u8*    woutT = (u8*)   alloc((size_t)E_DIM * E_DIM);
    u8*    w1T   = (u8*)   alloc((size_t)HID_DIM * E_DIM);
    u8*    w2T   = (u8*)   alloc((size_t)E_DIM * HID_DIM);

    wconv_f8<<<dim3((3 * E_DIM) / 64, E_DIM / 64), 256, 0, stream>>>(qkvw, wqkvT, E_DIM, 3 * E_DIM);
    wconv_f8<<<dim3(E_DIM / 64, E_DIM / 64), 256, 0, stream>>>(outw, woutT, E_DIM, E_DIM);
    wconv_f8<<<dim3(HID_DIM / 64, E_DIM / 64), 256, 0, stream>>>(w1, w1T, E_DIM, HID_DIM);
    wconv_f8<<<dim3(E_DIM / 64, HID_DIM / 64), 256, 0, stream>>>(w2, w2T, HID_DIM, E_DIM);

    ln_f8<<<BL / 4, 256, 0, stream>>>(x, ln1g, ln1b, hbuf);
    gemm_f8<E_DIM, 256, 0, false, false><<<(BL / 128) * 6, 512, 0, stream>>>(
        hbuf, wqkvT, qkvb, nullptr, qkvB, BL, 3 * E_DIM, 6);
    attn_mfma<<<dim3(32, 32), 256, 0, stream>>>(qkvB, obuf);
    gemm_f8<E_DIM, 128, 1, true, false><<<(BL / 128) * 4, 512, 0, stream>>>(
        obuf, woutT, outb, x, x2, BL, E_DIM, 4);
    ln_f8<<<BL / 4, 256, 0, stream>>>(x2, ln2g, ln2b, h2);
    gemm_f8<E_DIM, 256, 2, false, true><<<(BL / 128) * 8, 512, 0, stream>>>(
        h2, w1T, b1, nullptr, g1, BL, HID_DIM, 8);
    gemm_f8<HID_DIM, 128, 1, true, false><<<(BL / 128) * 4, 512, 0, stream>>>(
        g1, w2T, b2, x2, outp, BL, E_DIM, 4);
}

// Round 17
// 134.257 us; speedup vs baseline: 1.8368x; 1.0013x over previous
//
#include <hip/hip_runtime.h>
#include <math.h>

typedef unsigned char u8;
typedef unsigned short u16;
typedef unsigned int u32;
typedef __attribute__((ext_vector_type(4))) float f32x4;
typedef __attribute__((ext_vector_type(8))) short short8;

#define B_DIM 2
#define L_SEQ 4096
#define E_DIM 512
#define NH 8
#define HD 64
#define HID_DIM 2048
#define BL (B_DIM * L_SEQ)

__device__ __forceinline__ float bf2f(u16 u) {
    union { u32 i; float f; } v; v.i = ((u32)u) << 16; return v.f;
}
__device__ __forceinline__ u16 f2bf(float f) {
    union { float f; u32 i; } v; v.f = f;
    u32 r = v.i + 0x7fffu + ((v.i >> 16) & 1u);
    return (u16)(r >> 16);
}
__device__ __forceinline__ u32 pk2_fp8(float a, float b) {
    return (u32)__builtin_amdgcn_cvt_pk_fp8_f32(a, b, 0, false); // byte0=fp8(a), byte1=fp8(b)
}
__device__ __forceinline__ u8 f2fp8(float a) { return (u8)(pk2_fp8(a, a) & 0xffu); }
__device__ __forceinline__ float gelu_f(float v) {
    float y = fminf(0.7978845608f * (v + 0.044715f * v * v * v), 15.f);
    float t = __expf(2.f * y);
    return v * (t / (t + 1.f));
}

#define GLOAD_LDS16(gp, lp) __builtin_amdgcn_global_load_lds( \
    (const __attribute__((address_space(1))) void*)(gp),      \
    (__attribute__((address_space(3))) void*)(lp), 16, 0, 0)

template<int VM> __device__ __forceinline__ void waitvm() {
    asm volatile("s_waitcnt vmcnt(%0)" :: "n"(VM) : "memory");
}

// -------- weight convert+transpose: f32 [Kd][Nd] -> fp8 e4m3 [Nd][Kd], PRESCALED x32 --------
// (w ~ N(0,0.02) is subnormal in e4m3 -> ~20% rel err; x32 -> N(0,0.64), ~2%. Epilogue /32.)
__global__ __launch_bounds__(256) void wconv_f8(const float* __restrict__ in,
                                                u8* __restrict__ out, int Kd, int Nd) {
    __shared__ u8 t[64][96];           // row stride 96 keeps 16B-aligned chunks
    const int k0 = blockIdx.y * 64, n0 = blockIdx.x * 64;
    const int tid = threadIdx.x;
    const int col4 = tid & 15, rowb = tid >> 4;
#pragma unroll
    for (int i = 0; i < 4; ++i) {
        const int k = rowb + i * 16;
        const float4 v = *(const float4*)(in + (size_t)(k0 + k) * Nd + n0 + col4 * 4);
        const u32 p01 = pk2_fp8(v.x * 32.f, v.y * 32.f);
        const u32 p23 = pk2_fp8(v.z * 32.f, v.w * 32.f);
        t[col4 * 4 + 0][k] = (u8)(p01 & 0xff);
        t[col4 * 4 + 1][k] = (u8)((p01 >> 8) & 0xff);
        t[col4 * 4 + 2][k] = (u8)(p23 & 0xff);
        t[col4 * 4 + 3][k] = (u8)((p23 >> 8) & 0xff);
    }
    __syncthreads();
    const int n = tid >> 2, ch = tid & 3;
    u8* dst = out + (size_t)(n0 + n) * Kd + k0 + ch * 16;
    *(short8*)dst = *(const short8*)&t[n][ch * 16];
}

// ---------------- LayerNorm: f32 [rows][512] -> fp8 [rows][512], wave per row ----------------
__global__ __launch_bounds__(256) void ln_f8(const float* __restrict__ x,
                                             const float* __restrict__ g,
                                             const float* __restrict__ b,
                                             u8* __restrict__ out) {
    const int row = blockIdx.x * 4 + (threadIdx.x >> 6);
    const int lane = threadIdx.x & 63;
    const float4* xr = (const float4*)(x + (size_t)row * E_DIM);
    const float4 v0 = xr[lane];
    const float4 v1 = xr[lane + 64];
    float s  = v0.x + v0.y + v0.z + v0.w + v1.x + v1.y + v1.z + v1.w;
    float s2 = v0.x*v0.x + v0.y*v0.y + v0.z*v0.z + v0.w*v0.w
             + v1.x*v1.x + v1.y*v1.y + v1.z*v1.z + v1.w*v1.w;
#pragma unroll
    for (int off = 32; off > 0; off >>= 1) {
        s  += __shfl_xor(s, off);
        s2 += __shfl_xor(s2, off);
    }
    const float mu = s * (1.f / E_DIM);
    const float rs = rsqrtf(s2 * (1.f / E_DIM) - mu * mu + 1e-5f);
    const float4 g0 = ((const float4*)g)[lane], g1 = ((const float4*)g)[lane + 64];
    const float4 b0 = ((const float4*)b)[lane], b1 = ((const float4*)b)[lane + 64];
    const float a0 = (v0.x - mu) * rs * g0.x + b0.x;
    const float a1 = (v0.y - mu) * rs * g0.y + b0.y;
    const float a2 = (v0.z - mu) * rs * g0.z + b0.z;
    const float a3 = (v0.w - mu) * rs * g0.w + b0.w;
    const float a4 = (v1.x - mu) * rs * g1.x + b1.x;
    const float a5 = (v1.y - mu) * rs * g1.y + b1.y;
    const float a6 = (v1.z - mu) * rs * g1.z + b1.z;
    const float a7 = (v1.w - mu) * rs * g1.w + b1.w;
    u32* orow = (u32*)(out + (size_t)row * E_DIM);
    orow[lane]      = pk2_fp8(a0, a1) | (pk2_fp8(a2, a3) << 16);
    orow[lane + 64] = pk2_fp8(a4, a5) | (pk2_fp8(a6, a7) << 16);
}

// ---------------- fp8 GEMM: C[M][N] = A[M][K](e4m3) @ Bt[N][K](e4m3, x32) ------------------
// r10-verified skeleton (8 waves 2x4, 3-buffer ring, counted vmcnt 2L/L/0), BK=64, fp8 bytes.
// LDS layout per operand: [kg = ks*2+g2][row-group(16)][row][16B]; group offset = gr*256.
// Frag read = ds_read_b64 at (ks*2+(g>>1))*KGS + gr*256 + r*16 + (g&1)*8.
// Epilogue: acc * (1/32) [weight prescale] + bias (+gelu) (+res); OUT: 0=bf16, 1=f32, 2=fp8.
template<int K_T, int BN_T, int OUT, bool RES, bool GELU>
__global__ __launch_bounds__(512) void gemm_f8(const u8* __restrict__ A,
                                               const u8* __restrict__ Bt,
                                               const float* __restrict__ bias,
                                               const float* __restrict__ res,
                                               void* __restrict__ Cp,
                                               int M, int N, int nbx) {
    constexpr int K = K_T;
    constexpr int NT = K / 64;                 // BK=64 steps (8 or 32)
    constexpr int MR = 4;                      // BM=128 fixed
    constexpr int NR = BN_T / 64;              // 4 or 2
    constexpr int GA = 8;                      // A row-groups
    constexpr int GB = BN_T / 16;              // 16 or 8
    constexpr int LB = GB / 8;                 // B loads/wave (2 or 1); A loads/wave = 1
    constexpr int L = 1 + LB;
    constexpr int AKG_S = GA * 256;            // 2048
    constexpr int BKG_S = GB * 256;
    constexpr int ABYTES = 128 * 64;           // 8KB
    constexpr int BBYTES = BN_T * 64;
    constexpr int TILE = ABYTES + BBYTES;
    __shared__ u8 sb[3 * TILE];
    const int tid = threadIdx.x;
    const int wave = tid >> 6, lane = tid & 63;
    const int wr = wave >> 2, wc = wave & 3;   // 2 x 4 wave grid

    const int xcd = blockIdx.x & 7;
    const int q = blockIdx.x >> 3;
    const int bx = q % nbx;
    const int by = (q / nbx) * 8 + xcd;
    const int bm = by * 128, bn = bx * BN_T;

    f32x4 acc[MR][NR];
#pragma unroll
    for (int m = 0; m < MR; ++m)
#pragma unroll
        for (int n = 0; n < NR; ++n) acc[m][n] = 0.f;

    const int lrow = (lane >> 4) * 16 + (lane & 15);   // row within a 4-group span

    auto stage = [&](int buf, int t) {
        u8* dst0 = sb + buf * TILE;
        {   // A: load i = wave (GA=8)
            const int kg = wave >> 1, j = wave & 1;
            const u8* src = A + (size_t)(bm + j * 64 + lrow) * K
                            + t * 64 + (kg >> 1) * 32 + (kg & 1) * 16;
            GLOAD_LDS16(src, dst0 + kg * AKG_S + j * 1024);
        }
#pragma unroll
        for (int h = 0; h < LB; ++h) {         // B: loads i = wave*LB + h
            const int i = wave * LB + h;
            const int kg = i / (GB / 4), j = i % (GB / 4);
            const u8* src = Bt + (size_t)(bn + j * 64 + lrow) * K
                            + t * 64 + (kg >> 1) * 32 + (kg & 1) * 16;
            GLOAD_LDS16(src, dst0 + ABYTES + kg * BKG_S + j * 1024);
        }
    };

    auto compute = [&](int buf) {
        const u8* base = sb + buf * TILE;
        const int g = lane >> 4, r = lane & 15;
        const int sub = g >> 1, off8 = (g & 1) * 8;
#pragma unroll
        for (int ks = 0; ks < 2; ++ks) {
            long av[MR], bv[NR];
#pragma unroll
            for (int m = 0; m < MR; ++m)
                av[m] = *(const long*)(base + (ks * 2 + sub) * AKG_S
                                       + (wr * 4 + m) * 256 + r * 16 + off8);
#pragma unroll
            for (int n = 0; n < NR; ++n)
                bv[n] = *(const long*)(base + ABYTES + (ks * 2 + sub) * BKG_S
                                       + (wc * NR + n) * 256 + r * 16 + off8);
            __builtin_amdgcn_s_setprio(1);
#pragma unroll
            for (int m = 0; m < MR; ++m)
#pragma unroll
                for (int n = 0; n < NR; ++n)
                    acc[m][n] = __builtin_amdgcn_mfma_f32_16x16x32_fp8_fp8(av[m], bv[n], acc[m][n], 0, 0, 0);
            __builtin_amdgcn_s_setprio(0);
        }
    };

    stage(0, 0);
    stage(1, 1);
    int sbuf = 2, cbuf = 0;
    for (int t = 0; t < NT - 2; ++t) {
        stage(sbuf, t + 2);
        sbuf = (sbuf == 2) ? 0 : sbuf + 1;
        waitvm<2 * L>();                       // tile t landed; t+1, t+2 in flight
        __builtin_amdgcn_s_barrier();
        compute(cbuf);
        cbuf = (cbuf == 2) ? 0 : cbuf + 1;
        __builtin_amdgcn_s_barrier();
    }
    waitvm<L>();
    __builtin_amdgcn_s_barrier();
    compute(cbuf);
    cbuf = (cbuf == 2) ? 0 : cbuf + 1;
    __builtin_amdgcn_s_barrier();
    waitvm<0>();                               // last tile: full drain (r8 lesson)
    __builtin_amdgcn_s_barrier();
    compute(cbuf);

    const int ccol = lane & 15;
    const int crow = (lane >> 4) * 4;
#pragma unroll
    for (int n = 0; n < NR; ++n) {
        const int gc = bn + wc * (NR * 16) + n * 16 + ccol;
        const float bi = bias[gc];
#pragma unroll
        for (int m = 0; m < MR; ++m) {
            const int gr0 = bm + wr * 64 + m * 16 + crow;
#pragma unroll
            for (int j = 0; j < 4; ++j) {
                float v = acc[m][n][j] * 0.03125f + bi;   // /32 weight prescale
                if (GELU) v = gelu_f(v);
                const size_t idx = (size_t)(gr0 + j) * N + gc;
                if (RES) v += res[idx];
                if (OUT == 0)      ((u16*)Cp)[idx] = f2bf(v);
                else if (OUT == 1) ((float*)Cp)[idx] = v;
                else               ((u8*)Cp)[idx] = f2fp8(v);
            }
        }
    }
}

// ---------------- dilated attention via parity split (bf16 qkv in, fp8 o out) ---------------
__global__ __launch_bounds__(256) void attn_mfma(const u16* __restrict__ qkv,
                                                 u8* __restrict__ o) {
    __shared__ u16 K_lds[32 * 64];
    __shared__ u16 V_lds[32 * 64];
    const int tid = threadIdx.x;
    const int w = tid >> 6, lane = tid & 63;
    const int g = lane >> 4, q = lane & 15;
    const int qt = blockIdx.x, bph = blockIdx.y;
    const int b = bph >> 4, p = (bph >> 3) & 1, h = bph & 7;
    const int q0 = qt * 64;

    const size_t rowstride = 3 * E_DIM;
    const u16* qbase = qkv + (size_t)b * L_SEQ * rowstride + h * HD;

    const int qmin = q0 + w * 16, qmax = qmin + 15;
    const int qs_lane = qmin + q;
    const int qi = 2 * qs_lane + p;

    short8 qfrag[2];
    qfrag[0] = *(const short8*)(qbase + (size_t)qi * rowstride + g * 8);
    qfrag[1] = *(const short8*)(qbase + (size_t)qi * rowstride + 32 + g * 8);

    f32x4 oacc[4];
#pragma unroll
    for (int dt = 0; dt < 4; ++dt) oacc[dt] = 0.f;
    float m = -1e30f, l = 0.f;

    for (int s = 0; s < 6; ++s) {
        const int ks0 = q0 - 128 + 32 * s;
        if (ks0 >= 0) {
            const int r = 8 * w + (lane >> 3);
            const int gr = lane & 7;
            const size_t krow = (size_t)(2 * (ks0 + r) + p) * rowstride;
            const u16* ksrc = qbase + krow + E_DIM + 8 * (gr ^ (r & 7));
            const u16* vsrc = qbase + krow + 2 * E_DIM + 8 * gr;
            GLOAD_LDS16(ksrc, &K_lds[w * 512]);
            GLOAD_LDS16(vsrc, &V_lds[w * 512]);
        }
        __syncthreads();
        const bool active = (ks0 >= 0) && (ks0 <= qmax) && (ks0 + 31 >= qmin - 128);
        if (active) {
            f32x4 st[2];
            st[0] = 0.f; st[1] = 0.f;
#pragma unroll
            for (int t = 0; t < 2; ++t) {
#pragma unroll
                for (int c = 0; c < 2; ++c) {
                    const int kk = t * 16 + q;
                    const int gs = (c * 4 + g) ^ (kk & 7);
                    short8 kf = *(const short8*)&K_lds[kk * 64 + gs * 8];
                    st[t] = __builtin_amdgcn_mfma_f32_16x16x32_bf16(kf, qfrag[c], st[t], 0, 0, 0);
                }
            }
            float sv[2][4];
            float bm = -3.0e38f;
#pragma unroll
            for (int t = 0; t < 2; ++t)
#pragma unroll
                for (int j = 0; j < 4; ++j) {
                    const int kk = ks0 + t * 16 + 4 * g + j;
                    float x = st[t][j] * 0.125f;
                    const bool ok = (kk <= qs_lane) && (qs_lane - kk <= 128);
                    x = ok ? x : -3.0e38f;
                    sv[t][j] = x;
                    bm = fmaxf(bm, x);
                }
            bm = fmaxf(bm, __shfl_xor(bm, 16));
            bm = fmaxf(bm, __shfl_xor(bm, 32));
            const float mn = fmaxf(m, bm);
            const float sc = __expf(m - mn);
            m = mn;
            float rs = 0.f;
            u32 pk[2][2];
#pragma unroll
            for (int t = 0; t < 2; ++t) {
                const float e0 = __expf(sv[t][0] - mn), e1 = __expf(sv[t][1] - mn);
                const float e2 = __expf(sv[t][2] - mn), e3 = __expf(sv[t][3] - mn);
                rs += (e0 + e1) + (e2 + e3);
                pk[t][0] = (u32)f2bf(e0) | ((u32)f2bf(e1) << 16);
                pk[t][1] = (u32)f2bf(e2) | ((u32)f2bf(e3) << 16);
            }
            rs += __shfl_xor(rs, 16);
            rs += __shfl_xor(rs, 32);
            l = l * sc + rs;
#pragma unroll
            for (int dt = 0; dt < 4; ++dt) oacc[dt] *= sc;
            union { u32 w4[4]; short8 s8; } bfr;
#pragma unroll
            for (int r = 0; r < 4; ++r) {
                const int src = (((g << 1) + (r >> 1)) & 3) * 16 + q;
                const int w0 = __shfl((int)pk[0][r & 1], src);
                const int w1 = __shfl((int)pk[1][r & 1], src);
                bfr.w4[r] = (g & 2) ? (u32)w1 : (u32)w0;
            }
#pragma unroll
            for (int dt = 0; dt < 4; ++dt) {
                union { u16 h8[8]; short8 s8; } vf;
#pragma unroll
                for (int e = 0; e < 8; ++e)
                    vf.h8[e] = V_lds[(8 * g + e) * 64 + dt * 16 + q];
                oacc[dt] = __builtin_amdgcn_mfma_f32_16x16x32_bf16(vf.s8, bfr.s8, oacc[dt], 0, 0, 0);
            }
        }
        __syncthreads();
    }
    const float inv = 1.f / l;
    u8* obase = o + ((size_t)(b * L_SEQ) + (size_t)qi) * E_DIM + h * HD;
#pragma unroll
    for (int dt = 0; dt < 4; ++dt) {
        const u32 pw = pk2_fp8(oacc[dt][0] * inv, oacc[dt][1] * inv)
                     | (pk2_fp8(oacc[dt][2] * inv, oacc[dt][3] * inv) << 16);
        *(u32*)(obase + dt * 16 + 4 * g) = pw;
    }
}

// --------------------------------------------------------------------------------------------
extern "C" void kernel_launch(void* const* d_in, const int* in_sizes, int n_in,
                              void* d_out, int out_size, void* d_ws, size_t ws_size,
                              hipStream_t stream) {
    const float* x    = (const float*)d_in[0];
    const float* ln1g = (const float*)d_in[1];
    const float* ln1b = (const float*)d_in[2];
    const float* qkvw = (const float*)d_in[3];
    const float* qkvb = (const float*)d_in[4];
    const float* outw = (const float*)d_in[5];
    const float* outb = (const float*)d_in[6];
    const float* ln2g = (const float*)d_in[7];
    const float* ln2b = (const float*)d_in[8];
    const float* w1   = (const float*)d_in[9];
    const float* b1   = (const float*)d_in[10];
    const float* w2   = (const float*)d_in[11];
    const float* b2   = (const float*)d_in[12];
    float* outp = (float*)d_out;

    char* ws = (char*)d_ws;
    size_t off = 0;
    auto alloc = [&](size_t bytes) {
        void* p = ws + off;
        off += (bytes + 255) & ~(size_t)255;
        return p;
    };
    u8*    hbuf  = (u8*)   alloc((size_t)BL * E_DIM);
    u16*   qkvB  = (u16*)  alloc((size_t)BL * 3 * E_DIM * 2);
    u8*    obuf  = (u8*)   alloc((size_t)BL * E_DIM);
    float* x2    = (float*)alloc((size_t)BL * E_DIM * 4);
    u8*    h2    = (u8*)   alloc((size_t)BL * E_DIM);
    u8*    g1    = (u8*)   alloc((size_t)BL * HID_DIM);
    u8*    wqkvT = (u8*)   alloc((size_t)3 * E_DIM * E_DIM);
    u8*    woutT = (u8*)   alloc((size_t)E_DIM * E_DIM);
    u8*    w1T   = (u8*)   alloc((size_t)HID_DIM * E_DIM);
    u8*    w2T   = (u8*)   alloc((size_t)E_DIM * HID_DIM);

    wconv_f8<<<dim3((3 * E_DIM) / 64, E_DIM / 64), 256, 0, stream>>>(qkvw, wqkvT, E_DIM, 3 * E_DIM);
    wconv_f8<<<dim3(E_DIM / 64, E_DIM / 64), 256, 0, stream>>>(outw, woutT, E_DIM, E_DIM);
    wconv_f8<<<dim3(HID_DIM / 64, E_DIM / 64), 256, 0, stream>>>(w1, w1T, E_DIM, HID_DIM);
    wconv_f8<<<dim3(E_DIM / 64, HID_DIM / 64), 256, 0, stream>>>(w2, w2T, HID_DIM, E_DIM);

    ln_f8<<<BL / 4, 256, 0, stream>>>(x, ln1g, ln1b, hbuf);
    gemm_f8<E_DIM, 256, 0, false, false><<<(BL / 128) * 6, 512, 0, stream>>>(
        hbuf, wqkvT, qkvb, nullptr, qkvB, BL, 3 * E_DIM, 6);
    attn_mfma<<<dim3(32, 32), 256, 0, stream>>>(qkvB, obuf);
    gemm_f8<E_DIM, 128, 1, true, false><<<(BL / 128) * 4, 512, 0, stream>>>(
        obuf, woutT, outb, x, x2, BL, E_DIM, 4);
    ln_f8<<<BL / 4, 256, 0, stream>>>(x2, ln2g, ln2b, h2);
    gemm_f8<E_DIM, 256, 2, false, true><<<(BL / 128) * 8, 512, 0, stream>>>(
        h2, w1T, b1, nullptr, g1, BL, HID_DIM, 8);
    gemm_f8<HID_DIM, 128, 1, true, false><<<(BL / 128) * 4, 512, 0, stream>>>(
        g1, w2T, b2, x2, outp, BL, E_DIM, 4);
}

// Round 19
// 121.940 us; speedup vs baseline: 2.0224x; 1.1010x over previous
//
#include <hip/hip_runtime.h>
#include <math.h>

typedef unsigned char u8;
typedef unsigned short u16;
typedef unsigned int u32;
typedef __attribute__((ext_vector_type(4))) float f32x4;
typedef __attribute__((ext_vector_type(8))) short short8;

#define B_DIM 2
#define L_SEQ 4096
#define E_DIM 512
#define NH 8
#define HD 64
#define HID_DIM 2048
#define BL (B_DIM * L_SEQ)

__device__ __forceinline__ float bf2f(u16 u) {
    union { u32 i; float f; } v; v.i = ((u32)u) << 16; return v.f;
}
__device__ __forceinline__ u16 f2bf(float f) {
    union { float f; u32 i; } v; v.f = f;
    u32 r = v.i + 0x7fffu + ((v.i >> 16) & 1u);
    return (u16)(r >> 16);
}
__device__ __forceinline__ u32 pk2_fp8(float a, float b) {
    return (u32)__builtin_amdgcn_cvt_pk_fp8_f32(a, b, 0, false);
}
__device__ __forceinline__ u8 f2fp8(float a) { return (u8)(pk2_fp8(a, a) & 0xffu); }
__device__ __forceinline__ float gelu_f(float v) {
    float y = fminf(0.7978845608f * (v + 0.044715f * v * v * v), 15.f);
    float t = __expf(2.f * y);
    return v * (t / (t + 1.f));
}

#define GLOAD_LDS16(gp, lp) __builtin_amdgcn_global_load_lds( \
    (const __attribute__((address_space(1))) void*)(gp),      \
    (__attribute__((address_space(3))) void*)(lp), 16, 0, 0)

template<int VM> __device__ __forceinline__ void waitvm() {
    asm volatile("s_waitcnt vmcnt(%0)" :: "n"(VM) : "memory");
}

// ---------------- prep: 4 weight-converts (f32->fp8^T, x32 prescale) + LN1, ONE kernel ------
// blocks [0, BL/4): LN1 rows; [BL/4, BL/4+768): wconv tiles (qkv 192, out 64, w1 256, w2 256).
// r18 bug: launched 704 wconv blocks, not 768 -- last 64 w2 tiles stayed 0xAA poison.
__global__ __launch_bounds__(256) void prep(const float* __restrict__ qkvw,
                                            const float* __restrict__ outw,
                                            const float* __restrict__ w1,
                                            const float* __restrict__ w2,
                                            u8* __restrict__ wqkvT, u8* __restrict__ woutT,
                                            u8* __restrict__ w1T, u8* __restrict__ w2T,
                                            const float* __restrict__ x,
                                            const float* __restrict__ g,
                                            const float* __restrict__ b,
                                            u8* __restrict__ hbuf) {
    __shared__ u8 t[64][96];
    int bid = blockIdx.x;
    const int tid = threadIdx.x;
    if (bid < BL / 4) {
        // ---- LN1: f32 in -> fp8 out, wave per row ----
        const int row = bid * 4 + (tid >> 6);
        const int lane = tid & 63;
        const float4* xr = (const float4*)(x + (size_t)row * E_DIM);
        const float4 v0 = xr[lane];
        const float4 v1 = xr[lane + 64];
        float s  = v0.x + v0.y + v0.z + v0.w + v1.x + v1.y + v1.z + v1.w;
        float s2 = v0.x*v0.x + v0.y*v0.y + v0.z*v0.z + v0.w*v0.w
                 + v1.x*v1.x + v1.y*v1.y + v1.z*v1.z + v1.w*v1.w;
#pragma unroll
        for (int off = 32; off > 0; off >>= 1) {
            s  += __shfl_xor(s, off);
            s2 += __shfl_xor(s2, off);
        }
        const float mu = s * (1.f / E_DIM);
        const float rs = rsqrtf(s2 * (1.f / E_DIM) - mu * mu + 1e-5f);
        const float4 g0 = ((const float4*)g)[lane], g1 = ((const float4*)g)[lane + 64];
        const float4 b0 = ((const float4*)b)[lane], b1 = ((const float4*)b)[lane + 64];
        const float a0 = (v0.x - mu) * rs * g0.x + b0.x;
        const float a1 = (v0.y - mu) * rs * g0.y + b0.y;
        const float a2 = (v0.z - mu) * rs * g0.z + b0.z;
        const float a3 = (v0.w - mu) * rs * g0.w + b0.w;
        const float a4 = (v1.x - mu) * rs * g1.x + b1.x;
        const float a5 = (v1.y - mu) * rs * g1.y + b1.y;
        const float a6 = (v1.z - mu) * rs * g1.z + b1.z;
        const float a7 = (v1.w - mu) * rs * g1.w + b1.w;
        u32* orow = (u32*)(hbuf + (size_t)row * E_DIM);
        orow[lane]      = pk2_fp8(a0, a1) | (pk2_fp8(a2, a3) << 16);
        orow[lane + 64] = pk2_fp8(a4, a5) | (pk2_fp8(a6, a7) << 16);
        return;
    }
    bid -= BL / 4;
    const float* in; u8* out; int Kd, Nd, nbx;
    if (bid < 192)      {            in = qkvw; out = wqkvT; Kd = E_DIM;   Nd = 3 * E_DIM; nbx = 24; }
    else if (bid < 256) { bid -= 192; in = outw; out = woutT; Kd = E_DIM;   Nd = E_DIM;     nbx = 8;  }
    else if (bid < 512) { bid -= 256; in = w1;   out = w1T;   Kd = E_DIM;   Nd = HID_DIM;   nbx = 32; }
    else                { bid -= 512; in = w2;   out = w2T;   Kd = HID_DIM; Nd = E_DIM;     nbx = 8;  }
    const int k0 = (bid / nbx) * 64, n0 = (bid % nbx) * 64;
    const int col4 = tid & 15, rowb = tid >> 4;
#pragma unroll
    for (int i = 0; i < 4; ++i) {
        const int k = rowb + i * 16;
        const float4 v = *(const float4*)(in + (size_t)(k0 + k) * Nd + n0 + col4 * 4);
        const u32 p01 = pk2_fp8(v.x * 32.f, v.y * 32.f);
        const u32 p23 = pk2_fp8(v.z * 32.f, v.w * 32.f);
        t[col4 * 4 + 0][k] = (u8)(p01 & 0xff);
        t[col4 * 4 + 1][k] = (u8)((p01 >> 8) & 0xff);
        t[col4 * 4 + 2][k] = (u8)(p23 & 0xff);
        t[col4 * 4 + 3][k] = (u8)((p23 >> 8) & 0xff);
    }
    __syncthreads();
    const int n = tid >> 2, ch = tid & 3;
    u8* dst = out + (size_t)(n0 + n) * Kd + k0 + ch * 16;
    *(short8*)dst = *(const short8*)&t[n][ch * 16];
}

// ---------------- LN2: bf16 in -> fp8 out, wave per row (512 = 64 lanes x 8) ----------------
__global__ __launch_bounds__(256) void ln_b(const u16* __restrict__ x,
                                            const float* __restrict__ g,
                                            const float* __restrict__ b,
                                            u8* __restrict__ out) {
    const int row = blockIdx.x * 4 + (threadIdx.x >> 6);
    const int lane = threadIdx.x & 63;
    const short8 v = *(const short8*)(x + (size_t)row * E_DIM + lane * 8);
    float f[8];
#pragma unroll
    for (int j = 0; j < 8; ++j) f[j] = bf2f((u16)v[j]);
    float s = 0.f, s2 = 0.f;
#pragma unroll
    for (int j = 0; j < 8; ++j) { s += f[j]; s2 += f[j] * f[j]; }
#pragma unroll
    for (int off = 32; off > 0; off >>= 1) {
        s  += __shfl_xor(s, off);
        s2 += __shfl_xor(s2, off);
    }
    const float mu = s * (1.f / E_DIM);
    const float rs = rsqrtf(s2 * (1.f / E_DIM) - mu * mu + 1e-5f);
    const float4 g0 = ((const float4*)g)[lane * 2], g1 = ((const float4*)g)[lane * 2 + 1];
    const float4 b0 = ((const float4*)b)[lane * 2], b1 = ((const float4*)b)[lane * 2 + 1];
    float a[8];
    a[0] = (f[0] - mu) * rs * g0.x + b0.x;
    a[1] = (f[1] - mu) * rs * g0.y + b0.y;
    a[2] = (f[2] - mu) * rs * g0.z + b0.z;
    a[3] = (f[3] - mu) * rs * g0.w + b0.w;
    a[4] = (f[4] - mu) * rs * g1.x + b1.x;
    a[5] = (f[5] - mu) * rs * g1.y + b1.y;
    a[6] = (f[6] - mu) * rs * g1.z + b1.z;
    a[7] = (f[7] - mu) * rs * g1.w + b1.w;
    uint2 pw;
    pw.x = pk2_fp8(a[0], a[1]) | (pk2_fp8(a[2], a[3]) << 16);
    pw.y = pk2_fp8(a[4], a[5]) | (pk2_fp8(a[6], a[7]) << 16);
    *(uint2*)(out + (size_t)row * E_DIM + lane * 8) = pw;
}

// ---------------- fp8 GEMM: C[M][N] = A[M][K](e4m3) @ Bt[N][K](e4m3, x32) ------------------
// BN=256: verified 3-buffer depth-2 (waits 2L/L/0). BN=128: 4-buffer depth-3 (r5-verified
// schedule: waits 3L/2L/L/0) -- deeper prefetch for the 1-block/CU launches.
// OUT: 0=bf16, 1=f32, 2=fp8. RESV: 0=none, 1=f32, 2=bf16. Epilogue: acc/32 + bias (+gelu)(+res).
template<int K_T, int BN_T, int OUT, int RESV, bool GELU>
__global__ __launch_bounds__(512) void gemm_f8(const u8* __restrict__ A,
                                               const u8* __restrict__ Bt,
                                               const float* __restrict__ bias,
                                               const void* __restrict__ resv,
                                               void* __restrict__ Cp,
                                               int M, int N, int nbx) {
    constexpr int K = K_T;
    constexpr int NT = K / 64;
    constexpr int MR = 4;
    constexpr int NR = BN_T / 64;
    constexpr int GA = 8;
    constexpr int GB = BN_T / 16;
    constexpr int LB = GB / 8;
    constexpr int L = 1 + LB;
    constexpr int AKG_S = GA * 256;
    constexpr int BKG_S = GB * 256;
    constexpr int ABYTES = 128 * 64;
    constexpr int BBYTES = BN_T * 64;
    constexpr int TILE = ABYTES + BBYTES;
    constexpr int NBUF = (BN_T == 128) ? 4 : 3;
    __shared__ u8 sb[NBUF * TILE];
    const int tid = threadIdx.x;
    const int wave = tid >> 6, lane = tid & 63;
    const int wr = wave >> 2, wc = wave & 3;

    const int xcd = blockIdx.x & 7;
    const int q = blockIdx.x >> 3;
    const int bx = q % nbx;
    const int by = (q / nbx) * 8 + xcd;
    const int bm = by * 128, bn = bx * BN_T;

    f32x4 acc[MR][NR];
#pragma unroll
    for (int m = 0; m < MR; ++m)
#pragma unroll
        for (int n = 0; n < NR; ++n) acc[m][n] = 0.f;

    const int lrow = (lane >> 4) * 16 + (lane & 15);

    auto stage = [&](int buf, int t) {
        u8* dst0 = sb + buf * TILE;
        {
            const int kg = wave >> 1, j = wave & 1;
            const u8* src = A + (size_t)(bm + j * 64 + lrow) * K
                            + t * 64 + (kg >> 1) * 32 + (kg & 1) * 16;
            GLOAD_LDS16(src, dst0 + kg * AKG_S + j * 1024);
        }
#pragma unroll
        for (int h = 0; h < LB; ++h) {
            const int i = wave * LB + h;
            const int kg = i / (GB / 4), j = i % (GB / 4);
            const u8* src = Bt + (size_t)(bn + j * 64 + lrow) * K
                            + t * 64 + (kg >> 1) * 32 + (kg & 1) * 16;
            GLOAD_LDS16(src, dst0 + ABYTES + kg * BKG_S + j * 1024);
        }
    };

    auto compute = [&](int buf) {
        const u8* base = sb + buf * TILE;
        const int g = lane >> 4, r = lane & 15;
        const int sub = g >> 1, off8 = (g & 1) * 8;
#pragma unroll
        for (int ks = 0; ks < 2; ++ks) {
            long av[MR], bv[NR];
#pragma unroll
            for (int m = 0; m < MR; ++m)
                av[m] = *(const long*)(base + (ks * 2 + sub) * AKG_S
                                       + (wr * 4 + m) * 256 + r * 16 + off8);
#pragma unroll
            for (int n = 0; n < NR; ++n)
                bv[n] = *(const long*)(base + ABYTES + (ks * 2 + sub) * BKG_S
                                       + (wc * NR + n) * 256 + r * 16 + off8);
            __builtin_amdgcn_s_setprio(1);
#pragma unroll
            for (int m = 0; m < MR; ++m)
#pragma unroll
                for (int n = 0; n < NR; ++n)
                    acc[m][n] = __builtin_amdgcn_mfma_f32_16x16x32_fp8_fp8(av[m], bv[n], acc[m][n], 0, 0, 0);
            __builtin_amdgcn_s_setprio(0);
        }
    };

    if constexpr (BN_T == 128) {
        // 4-buffer depth-3: tile t -> buf t&3; waits 3L / 2L / L / 0.
        stage(0, 0);
        stage(1, 1);
        stage(2, 2);
        for (int t = 0; t < NT - 3; ++t) {
            stage((t + 3) & 3, t + 3);
            waitvm<3 * L>();
            __builtin_amdgcn_s_barrier();
            compute(t & 3);
            __builtin_amdgcn_s_barrier();
        }
        waitvm<2 * L>();
        __builtin_amdgcn_s_barrier();
        compute((NT - 3) & 3);
        __builtin_amdgcn_s_barrier();
        waitvm<L>();
        __builtin_amdgcn_s_barrier();
        compute((NT - 2) & 3);
        __builtin_amdgcn_s_barrier();
        waitvm<0>();
        __builtin_amdgcn_s_barrier();
        compute((NT - 1) & 3);
    } else {
        // 3-buffer depth-2 (verified r17 path): waits 2L / L / 0.
        stage(0, 0);
        stage(1, 1);
        int sbuf = 2, cbuf = 0;
        for (int t = 0; t < NT - 2; ++t) {
            stage(sbuf, t + 2);
            sbuf = (sbuf == 2) ? 0 : sbuf + 1;
            waitvm<2 * L>();
            __builtin_amdgcn_s_barrier();
            compute(cbuf);
            cbuf = (cbuf == 2) ? 0 : cbuf + 1;
            __builtin_amdgcn_s_barrier();
        }
        waitvm<L>();
        __builtin_amdgcn_s_barrier();
        compute(cbuf);
        cbuf = (cbuf == 2) ? 0 : cbuf + 1;
        __builtin_amdgcn_s_barrier();
        waitvm<0>();
        __builtin_amdgcn_s_barrier();
        compute(cbuf);
    }

    const int ccol = lane & 15;
    const int crow = (lane >> 4) * 4;
#pragma unroll
    for (int n = 0; n < NR; ++n) {
        const int gc = bn + wc * (NR * 16) + n * 16 + ccol;
        const float bi = bias[gc];
#pragma unroll
        for (int m = 0; m < MR; ++m) {
            const int gr0 = bm + wr * 64 + m * 16 + crow;
#pragma unroll
            for (int j = 0; j < 4; ++j) {
                float v = acc[m][n][j] * 0.03125f + bi;   // /32 weight prescale
                if (GELU) v = gelu_f(v);
                const size_t idx = (size_t)(gr0 + j) * N + gc;
                if (RESV == 1)      v += ((const float*)resv)[idx];
                else if (RESV == 2) v += bf2f(((const u16*)resv)[idx]);
                if (OUT == 0)      ((u16*)Cp)[idx] = f2bf(v);
                else if (OUT == 1) ((float*)Cp)[idx] = v;
                else               ((u8*)Cp)[idx] = f2fp8(v);
            }
        }
    }
}

// ---------------- dilated attention via parity split (bf16 qkv in, fp8 o out) ---------------
__global__ __launch_bounds__(256) void attn_mfma(const u16* __restrict__ qkv,
                                                 u8* __restrict__ o) {
    __shared__ u16 K_lds[32 * 64];
    __shared__ u16 V_lds[32 * 64];
    const int tid = threadIdx.x;
    const int w = tid >> 6, lane = tid & 63;
    const int g = lane >> 4, q = lane & 15;
    const int qt = blockIdx.x, bph = blockIdx.y;
    const int b = bph >> 4, p = (bph >> 3) & 1, h = bph & 7;
    const int q0 = qt * 64;

    const size_t rowstride = 3 * E_DIM;
    const u16* qbase = qkv + (size_t)b * L_SEQ * rowstride + h * HD;

    const int qmin = q0 + w * 16, qmax = qmin + 15;
    const int qs_lane = qmin + q;
    const int qi = 2 * qs_lane + p;

    short8 qfrag[2];
    qfrag[0] = *(const short8*)(qbase + (size_t)qi * rowstride + g * 8);
    qfrag[1] = *(const short8*)(qbase + (size_t)qi * rowstride + 32 + g * 8);

    f32x4 oacc[4];
#pragma unroll
    for (int dt = 0; dt < 4; ++dt) oacc[dt] = 0.f;
    float m = -1e30f, l = 0.f;

    for (int s = 0; s < 6; ++s) {
        const int ks0 = q0 - 128 + 32 * s;
        if (ks0 >= 0) {
            const int r = 8 * w + (lane >> 3);
            const int gr = lane & 7;
            const size_t krow = (size_t)(2 * (ks0 + r) + p) * rowstride;
            const u16* ksrc = qbase + krow + E_DIM + 8 * (gr ^ (r & 7));
            const u16* vsrc = qbase + krow + 2 * E_DIM + 8 * gr;
            GLOAD_LDS16(ksrc, &K_lds[w * 512]);
            GLOAD_LDS16(vsrc, &V_lds[w * 512]);
        }
        __syncthreads();
        const bool active = (ks0 >= 0) && (ks0 <= qmax) && (ks0 + 31 >= qmin - 128);
        if (active) {
            f32x4 st[2];
            st[0] = 0.f; st[1] = 0.f;
#pragma unroll
            for (int t = 0; t < 2; ++t) {
#pragma unroll
                for (int c = 0; c < 2; ++c) {
                    const int kk = t * 16 + q;
                    const int gs = (c * 4 + g) ^ (kk & 7);
                    short8 kf = *(const short8*)&K_lds[kk * 64 + gs * 8];
                    st[t] = __builtin_amdgcn_mfma_f32_16x16x32_bf16(kf, qfrag[c], st[t], 0, 0, 0);
                }
            }
            float sv[2][4];
            float bm = -3.0e38f;
#pragma unroll
            for (int t = 0; t < 2; ++t)
#pragma unroll
                for (int j = 0; j < 4; ++j) {
                    const int kk = ks0 + t * 16 + 4 * g + j;
                    float x = st[t][j] * 0.125f;
                    const bool ok = (kk <= qs_lane) && (qs_lane - kk <= 128);
                    x = ok ? x : -3.0e38f;
                    sv[t][j] = x;
                    bm = fmaxf(bm, x);
                }
            bm = fmaxf(bm, __shfl_xor(bm, 16));
            bm = fmaxf(bm, __shfl_xor(bm, 32));
            const float mn = fmaxf(m, bm);
            const float sc = __expf(m - mn);
            m = mn;
            float rs = 0.f;
            u32 pk[2][2];
#pragma unroll
            for (int t = 0; t < 2; ++t) {
                const float e0 = __expf(sv[t][0] - mn), e1 = __expf(sv[t][1] - mn);
                const float e2 = __expf(sv[t][2] - mn), e3 = __expf(sv[t][3] - mn);
                rs += (e0 + e1) + (e2 + e3);
                pk[t][0] = (u32)f2bf(e0) | ((u32)f2bf(e1) << 16);
                pk[t][1] = (u32)f2bf(e2) | ((u32)f2bf(e3) << 16);
            }
            rs += __shfl_xor(rs, 16);
            rs += __shfl_xor(rs, 32);
            l = l * sc + rs;
#pragma unroll
            for (int dt = 0; dt < 4; ++dt) oacc[dt] *= sc;
            union { u32 w4[4]; short8 s8; } bfr;
#pragma unroll
            for (int r = 0; r < 4; ++r) {
                const int src = (((g << 1) + (r >> 1)) & 3) * 16 + q;
                const int w0 = __shfl((int)pk[0][r & 1], src);
                const int w1 = __shfl((int)pk[1][r & 1], src);
                bfr.w4[r] = (g & 2) ? (u32)w1 : (u32)w0;
            }
#pragma unroll
            for (int dt = 0; dt < 4; ++dt) {
                union { u16 h8[8]; short8 s8; } vf;
#pragma unroll
                for (int e = 0; e < 8; ++e)
                    vf.h8[e] = V_lds[(8 * g + e) * 64 + dt * 16 + q];
                oacc[dt] = __builtin_amdgcn_mfma_f32_16x16x32_bf16(vf.s8, bfr.s8, oacc[dt], 0, 0, 0);
            }
        }
        __syncthreads();
    }
    const float inv = 1.f / l;
    u8* obase = o + ((size_t)(b * L_SEQ) + (size_t)qi) * E_DIM + h * HD;
#pragma unroll
    for (int dt = 0; dt < 4; ++dt) {
        const u32 pw = pk2_fp8(oacc[dt][0] * inv, oacc[dt][1] * inv)
                     | (pk2_fp8(oacc[dt][2] * inv, oacc[dt][3] * inv) << 16);
        *(u32*)(obase + dt * 16 + 4 * g) = pw;
    }
}

// --------------------------------------------------------------------------------------------
extern "C" void kernel_launch(void* const* d_in, const int* in_sizes, int n_in,
                              void* d_out, int out_size, void* d_ws, size_t ws_size,
                              hipStream_t stream) {
    const float* x    = (const float*)d_in[0];
    const float* ln1g = (const float*)d_in[1];
    const float* ln1b = (const float*)d_in[2];
    const float* qkvw = (const float*)d_in[3];
    const float* qkvb = (const float*)d_in[4];
    const float* outw = (const float*)d_in[5];
    const float* outb = (const float*)d_in[6];
    const float* ln2g = (const float*)d_in[7];
    const float* ln2b = (const float*)d_in[8];
    const float* w1   = (const float*)d_in[9];
    const float* b1   = (const float*)d_in[10];
    const float* w2   = (const float*)d_in[11];
    const float* b2   = (const float*)d_in[12];
    float* outp = (float*)d_out;

    char* ws = (char*)d_ws;
    size_t off = 0;
    auto alloc = [&](size_t bytes) {
        void* p = ws + off;
        off += (bytes + 255) & ~(size_t)255;
        return p;
    };
    u8*    hbuf  = (u8*)   alloc((size_t)BL * E_DIM);
    u16*   qkvB  = (u16*)  alloc((size_t)BL * 3 * E_DIM * 2);
    u8*    obuf  = (u8*)   alloc((size_t)BL * E_DIM);
    u16*   x2    = (u16*)  alloc((size_t)BL * E_DIM * 2);
    u8*    h2    = (u8*)   alloc((size_t)BL * E_DIM);
    u8*    g1    = (u8*)   alloc((size_t)BL * HID_DIM);
    u8*    wqkvT = (u8*)   alloc((size_t)3 * E_DIM * E_DIM);
    u8*    woutT = (u8*)   alloc((size_t)E_DIM * E_DIM);
    u8*    w1T   = (u8*)   alloc((size_t)HID_DIM * E_DIM);
    u8*    w2T   = (u8*)   alloc((size_t)E_DIM * HID_DIM);

    prep<<<BL / 4 + 768, 256, 0, stream>>>(qkvw, outw, w1, w2, wqkvT, woutT, w1T, w2T,
                                           x, ln1g, ln1b, hbuf);
    gemm_f8<E_DIM, 256, 0, 0, false><<<(BL / 128) * 6, 512, 0, stream>>>(
        hbuf, wqkvT, qkvb, nullptr, qkvB, BL, 3 * E_DIM, 6);
    attn_mfma<<<dim3(32, 32), 256, 0, stream>>>(qkvB, obuf);
    gemm_f8<E_DIM, 128, 0, 1, false><<<(BL / 128) * 4, 512, 0, stream>>>(
        obuf, woutT, outb, x, x2, BL, E_DIM, 4);
    ln_b<<<BL / 4, 256, 0, stream>>>(x2, ln2g, ln2b, h2);
    gemm_f8<E_DIM, 256, 2, 0, true><<<(BL / 128) * 8, 512, 0, stream>>>(
        h2, w1T, b1, nullptr, g1, BL, HID_DIM, 8);
    gemm_f8<HID_DIM, 128, 1, 2, false><<<(BL / 128) * 4, 512, 0, stream>>>(
        g1, w2T, b2, x2, outp, BL, E_DIM, 4);
}

// Round 20
// 121.035 us; speedup vs baseline: 2.0375x; 1.0075x over previous
//
#include <hip/hip_runtime.h>
#include <math.h>

typedef unsigned char u8;
typedef unsigned short u16;
typedef unsigned int u32;
typedef __attribute__((ext_vector_type(4))) float f32x4;
typedef __attribute__((ext_vector_type(8))) short short8;

#define B_DIM 2
#define L_SEQ 4096
#define E_DIM 512
#define NH 8
#define HD 64
#define HID_DIM 2048
#define BL (B_DIM * L_SEQ)

__device__ __forceinline__ float bf2f(u16 u) {
    union { u32 i; float f; } v; v.i = ((u32)u) << 16; return v.f;
}
__device__ __forceinline__ u16 f2bf(float f) {
    union { float f; u32 i; } v; v.f = f;
    u32 r = v.i + 0x7fffu + ((v.i >> 16) & 1u);
    return (u16)(r >> 16);
}
__device__ __forceinline__ u32 pk2_fp8(float a, float b) {
    return (u32)__builtin_amdgcn_cvt_pk_fp8_f32(a, b, 0, false);
}
__device__ __forceinline__ u8 f2fp8(float a) { return (u8)(pk2_fp8(a, a) & 0xffu); }
__device__ __forceinline__ float gelu_f(float v) {
    float y = fminf(0.7978845608f * (v + 0.044715f * v * v * v), 15.f);
    float t = __expf(2.f * y);
    return v * (t / (t + 1.f));
}

#define GLOAD_LDS16(gp, lp) __builtin_amdgcn_global_load_lds( \
    (const __attribute__((address_space(1))) void*)(gp),      \
    (__attribute__((address_space(3))) void*)(lp), 16, 0, 0)

template<int VM> __device__ __forceinline__ void waitvm() {
    asm volatile("s_waitcnt vmcnt(%0)" :: "n"(VM) : "memory");
}

// ---------------- prep: 4 weight-converts (f32->fp8^T, x32 prescale) + LN1, ONE kernel ------
// blocks [0, BL/4): LN1 rows; [BL/4, BL/4+768): wconv tiles (qkv 192, out 64, w1 256, w2 256).
__global__ __launch_bounds__(256) void prep(const float* __restrict__ qkvw,
                                            const float* __restrict__ outw,
                                            const float* __restrict__ w1,
                                            const float* __restrict__ w2,
                                            u8* __restrict__ wqkvT, u8* __restrict__ woutT,
                                            u8* __restrict__ w1T, u8* __restrict__ w2T,
                                            const float* __restrict__ x,
                                            const float* __restrict__ g,
                                            const float* __restrict__ b,
                                            u8* __restrict__ hbuf) {
    __shared__ u8 t[64][96];
    int bid = blockIdx.x;
    const int tid = threadIdx.x;
    if (bid < BL / 4) {
        const int row = bid * 4 + (tid >> 6);
        const int lane = tid & 63;
        const float4* xr = (const float4*)(x + (size_t)row * E_DIM);
        const float4 v0 = xr[lane];
        const float4 v1 = xr[lane + 64];
        float s  = v0.x + v0.y + v0.z + v0.w + v1.x + v1.y + v1.z + v1.w;
        float s2 = v0.x*v0.x + v0.y*v0.y + v0.z*v0.z + v0.w*v0.w
                 + v1.x*v1.x + v1.y*v1.y + v1.z*v1.z + v1.w*v1.w;
#pragma unroll
        for (int off = 32; off > 0; off >>= 1) {
            s  += __shfl_xor(s, off);
            s2 += __shfl_xor(s2, off);
        }
        const float mu = s * (1.f / E_DIM);
        const float rs = rsqrtf(s2 * (1.f / E_DIM) - mu * mu + 1e-5f);
        const float4 g0 = ((const float4*)g)[lane], g1 = ((const float4*)g)[lane + 64];
        const float4 b0 = ((const float4*)b)[lane], b1 = ((const float4*)b)[lane + 64];
        const float a0 = (v0.x - mu) * rs * g0.x + b0.x;
        const float a1 = (v0.y - mu) * rs * g0.y + b0.y;
        const float a2 = (v0.z - mu) * rs * g0.z + b0.z;
        const float a3 = (v0.w - mu) * rs * g0.w + b0.w;
        const float a4 = (v1.x - mu) * rs * g1.x + b1.x;
        const float a5 = (v1.y - mu) * rs * g1.y + b1.y;
        const float a6 = (v1.z - mu) * rs * g1.z + b1.z;
        const float a7 = (v1.w - mu) * rs * g1.w + b1.w;
        u32* orow = (u32*)(hbuf + (size_t)row * E_DIM);
        orow[lane]      = pk2_fp8(a0, a1) | (pk2_fp8(a2, a3) << 16);
        orow[lane + 64] = pk2_fp8(a4, a5) | (pk2_fp8(a6, a7) << 16);
        return;
    }
    bid -= BL / 4;
    const float* in; u8* out; int Kd, Nd, nbx;
    if (bid < 192)      {            in = qkvw; out = wqkvT; Kd = E_DIM;   Nd = 3 * E_DIM; nbx = 24; }
    else if (bid < 256) { bid -= 192; in = outw; out = woutT; Kd = E_DIM;   Nd = E_DIM;     nbx = 8;  }
    else if (bid < 512) { bid -= 256; in = w1;   out = w1T;   Kd = E_DIM;   Nd = HID_DIM;   nbx = 32; }
    else                { bid -= 512; in = w2;   out = w2T;   Kd = HID_DIM; Nd = E_DIM;     nbx = 8;  }
    const int k0 = (bid / nbx) * 64, n0 = (bid % nbx) * 64;
    const int col4 = tid & 15, rowb = tid >> 4;
#pragma unroll
    for (int i = 0; i < 4; ++i) {
        const int k = rowb + i * 16;
        const float4 v = *(const float4*)(in + (size_t)(k0 + k) * Nd + n0 + col4 * 4);
        const u32 p01 = pk2_fp8(v.x * 32.f, v.y * 32.f);
        const u32 p23 = pk2_fp8(v.z * 32.f, v.w * 32.f);
        t[col4 * 4 + 0][k] = (u8)(p01 & 0xff);
        t[col4 * 4 + 1][k] = (u8)((p01 >> 8) & 0xff);
        t[col4 * 4 + 2][k] = (u8)(p23 & 0xff);
        t[col4 * 4 + 3][k] = (u8)((p23 >> 8) & 0xff);
    }
    __syncthreads();
    const int n = tid >> 2, ch = tid & 3;
    u8* dst = out + (size_t)(n0 + n) * Kd + k0 + ch * 16;
    *(short8*)dst = *(const short8*)&t[n][ch * 16];
}

// ---------------- LN2: bf16 in -> fp8 out, wave per row ----------------
__global__ __launch_bounds__(256) void ln_b(const u16* __restrict__ x,
                                            const float* __restrict__ g,
                                            const float* __restrict__ b,
                                            u8* __restrict__ out) {
    const int row = blockIdx.x * 4 + (threadIdx.x >> 6);
    const int lane = threadIdx.x & 63;
    const short8 v = *(const short8*)(x + (size_t)row * E_DIM + lane * 8);
    float f[8];
#pragma unroll
    for (int j = 0; j < 8; ++j) f[j] = bf2f((u16)v[j]);
    float s = 0.f, s2 = 0.f;
#pragma unroll
    for (int j = 0; j < 8; ++j) { s += f[j]; s2 += f[j] * f[j]; }
#pragma unroll
    for (int off = 32; off > 0; off >>= 1) {
        s  += __shfl_xor(s, off);
        s2 += __shfl_xor(s2, off);
    }
    const float mu = s * (1.f / E_DIM);
    const float rs = rsqrtf(s2 * (1.f / E_DIM) - mu * mu + 1e-5f);
    const float4 g0 = ((const float4*)g)[lane * 2], g1 = ((const float4*)g)[lane * 2 + 1];
    const float4 b0 = ((const float4*)b)[lane * 2], b1 = ((const float4*)b)[lane * 2 + 1];
    float a[8];
    a[0] = (f[0] - mu) * rs * g0.x + b0.x;
    a[1] = (f[1] - mu) * rs * g0.y + b0.y;
    a[2] = (f[2] - mu) * rs * g0.z + b0.z;
    a[3] = (f[3] - mu) * rs * g0.w + b0.w;
    a[4] = (f[4] - mu) * rs * g1.x + b1.x;
    a[5] = (f[5] - mu) * rs * g1.y + b1.y;
    a[6] = (f[6] - mu) * rs * g1.z + b1.z;
    a[7] = (f[7] - mu) * rs * g1.w + b1.w;
    uint2 pw;
    pw.x = pk2_fp8(a[0], a[1]) | (pk2_fp8(a[2], a[3]) << 16);
    pw.y = pk2_fp8(a[4], a[5]) | (pk2_fp8(a[6], a[7]) << 16);
    *(uint2*)(out + (size_t)row * E_DIM + lane * 8) = pw;
}

// ---------------- fp8 GEMM (r19-verified) -------------------------------------------------
template<int K_T, int BN_T, int OUT, int RESV, bool GELU>
__global__ __launch_bounds__(512) void gemm_f8(const u8* __restrict__ A,
                                               const u8* __restrict__ Bt,
                                               const float* __restrict__ bias,
                                               const void* __restrict__ resv,
                                               void* __restrict__ Cp,
                                               int M, int N, int nbx) {
    constexpr int K = K_T;
    constexpr int NT = K / 64;
    constexpr int MR = 4;
    constexpr int NR = BN_T / 64;
    constexpr int GA = 8;
    constexpr int GB = BN_T / 16;
    constexpr int LB = GB / 8;
    constexpr int L = 1 + LB;
    constexpr int AKG_S = GA * 256;
    constexpr int BKG_S = GB * 256;
    constexpr int ABYTES = 128 * 64;
    constexpr int BBYTES = BN_T * 64;
    constexpr int TILE = ABYTES + BBYTES;
    constexpr int NBUF = (BN_T == 128) ? 4 : 3;
    __shared__ u8 sb[NBUF * TILE];
    const int tid = threadIdx.x;
    const int wave = tid >> 6, lane = tid & 63;
    const int wr = wave >> 2, wc = wave & 3;

    const int xcd = blockIdx.x & 7;
    const int q = blockIdx.x >> 3;
    const int bx = q % nbx;
    const int by = (q / nbx) * 8 + xcd;
    const int bm = by * 128, bn = bx * BN_T;

    f32x4 acc[MR][NR];
#pragma unroll
    for (int m = 0; m < MR; ++m)
#pragma unroll
        for (int n = 0; n < NR; ++n) acc[m][n] = 0.f;

    const int lrow = (lane >> 4) * 16 + (lane & 15);

    auto stage = [&](int buf, int t) {
        u8* dst0 = sb + buf * TILE;
        {
            const int kg = wave >> 1, j = wave & 1;
            const u8* src = A + (size_t)(bm + j * 64 + lrow) * K
                            + t * 64 + (kg >> 1) * 32 + (kg & 1) * 16;
            GLOAD_LDS16(src, dst0 + kg * AKG_S + j * 1024);
        }
#pragma unroll
        for (int h = 0; h < LB; ++h) {
            const int i = wave * LB + h;
            const int kg = i / (GB / 4), j = i % (GB / 4);
            const u8* src = Bt + (size_t)(bn + j * 64 + lrow) * K
                            + t * 64 + (kg >> 1) * 32 + (kg & 1) * 16;
            GLOAD_LDS16(src, dst0 + ABYTES + kg * BKG_S + j * 1024);
        }
    };

    auto compute = [&](int buf) {
        const u8* base = sb + buf * TILE;
        const int g = lane >> 4, r = lane & 15;
        const int sub = g >> 1, off8 = (g & 1) * 8;
#pragma unroll
        for (int ks = 0; ks < 2; ++ks) {
            long av[MR], bv[NR];
#pragma unroll
            for (int m = 0; m < MR; ++m)
                av[m] = *(const long*)(base + (ks * 2 + sub) * AKG_S
                                       + (wr * 4 + m) * 256 + r * 16 + off8);
#pragma unroll
            for (int n = 0; n < NR; ++n)
                bv[n] = *(const long*)(base + ABYTES + (ks * 2 + sub) * BKG_S
                                       + (wc * NR + n) * 256 + r * 16 + off8);
            __builtin_amdgcn_s_setprio(1);
#pragma unroll
            for (int m = 0; m < MR; ++m)
#pragma unroll
                for (int n = 0; n < NR; ++n)
                    acc[m][n] = __builtin_amdgcn_mfma_f32_16x16x32_fp8_fp8(av[m], bv[n], acc[m][n], 0, 0, 0);
            __builtin_amdgcn_s_setprio(0);
        }
    };

    if constexpr (BN_T == 128) {
        stage(0, 0);
        stage(1, 1);
        stage(2, 2);
        for (int t = 0; t < NT - 3; ++t) {
            stage((t + 3) & 3, t + 3);
            waitvm<3 * L>();
            __builtin_amdgcn_s_barrier();
            compute(t & 3);
            __builtin_amdgcn_s_barrier();
        }
        waitvm<2 * L>();
        __builtin_amdgcn_s_barrier();
        compute((NT - 3) & 3);
        __builtin_amdgcn_s_barrier();
        waitvm<L>();
        __builtin_amdgcn_s_barrier();
        compute((NT - 2) & 3);
        __builtin_amdgcn_s_barrier();
        waitvm<0>();
        __builtin_amdgcn_s_barrier();
        compute((NT - 1) & 3);
    } else {
        stage(0, 0);
        stage(1, 1);
        int sbuf = 2, cbuf = 0;
        for (int t = 0; t < NT - 2; ++t) {
            stage(sbuf, t + 2);
            sbuf = (sbuf == 2) ? 0 : sbuf + 1;
            waitvm<2 * L>();
            __builtin_amdgcn_s_barrier();
            compute(cbuf);
            cbuf = (cbuf == 2) ? 0 : cbuf + 1;
            __builtin_amdgcn_s_barrier();
        }
        waitvm<L>();
        __builtin_amdgcn_s_barrier();
        compute(cbuf);
        cbuf = (cbuf == 2) ? 0 : cbuf + 1;
        __builtin_amdgcn_s_barrier();
        waitvm<0>();
        __builtin_amdgcn_s_barrier();
        compute(cbuf);
    }

    const int ccol = lane & 15;
    const int crow = (lane >> 4) * 4;
#pragma unroll
    for (int n = 0; n < NR; ++n) {
        const int gc = bn + wc * (NR * 16) + n * 16 + ccol;
        const float bi = bias[gc];
#pragma unroll
        for (int m = 0; m < MR; ++m) {
            const int gr0 = bm + wr * 64 + m * 16 + crow;
#pragma unroll
            for (int j = 0; j < 4; ++j) {
                float v = acc[m][n][j] * 0.03125f + bi;
                if (GELU) v = gelu_f(v);
                const size_t idx = (size_t)(gr0 + j) * N + gc;
                if (RESV == 1)      v += ((const float*)resv)[idx];
                else if (RESV == 2) v += bf2f(((const u16*)resv)[idx]);
                if (OUT == 0)      ((u16*)Cp)[idx] = f2bf(v);
                else if (OUT == 1) ((float*)Cp)[idx] = v;
                else               ((u8*)Cp)[idx] = f2fp8(v);
            }
        }
    }
}

// ---------------- dilated attention, FULL fp8 path (fp8 qkv in, fp8 o out) ------------------
// QK^T and PV via mfma_f32_16x16x32_fp8_fp8. K_lds swizzled on even slot bits
// (slot' = slot ^ (row&6)) so staging sources stay contiguous 16B; reads are 2-way (free).
__global__ __launch_bounds__(256) void attn_mfma(const u8* __restrict__ qkv,
                                                 u8* __restrict__ o) {
    __shared__ u8 K_lds[32 * 64];
    __shared__ u8 V_lds[32 * 64];
    const int tid = threadIdx.x;
    const int w = tid >> 6, lane = tid & 63;
    const int g = lane >> 4, q = lane & 15;
    const int qt = blockIdx.x, bph = blockIdx.y;
    const int b = bph >> 4, p = (bph >> 3) & 1, h = bph & 7;
    const int q0 = qt * 64;

    const size_t rowstride = 3 * E_DIM;                    // bytes (fp8)
    const u8* qbase = qkv + (size_t)b * L_SEQ * rowstride + h * HD;

    const int qmin = q0 + w * 16, qmax = qmin + 15;
    const int qs_lane = qmin + q;
    const int qi = 2 * qs_lane + p;

    long qfrag[2];
    qfrag[0] = *(const long*)(qbase + (size_t)qi * rowstride + g * 8);
    qfrag[1] = *(const long*)(qbase + (size_t)qi * rowstride + 32 + g * 8);

    f32x4 oacc[4];
#pragma unroll
    for (int dt = 0; dt < 4; ++dt) oacc[dt] = 0.f;
    float m = -1e30f, l = 0.f;

    for (int s = 0; s < 6; ++s) {
        const int ks0 = q0 - 128 + 32 * s;
        if (ks0 >= 0) {
            // waves 0,1 stage K rows (w&1)*16 + lane>>2 ; waves 2,3 stage V likewise.
            const int r = (w & 1) * 16 + (lane >> 2);
            const int ch = lane & 3;
            const size_t krow = (size_t)(2 * (ks0 + r) + p) * rowstride;
            if (w < 2) {
                const u8* ksrc = qbase + krow + E_DIM + (((2 * ch) ^ (r & 6)) * 8);
                GLOAD_LDS16(ksrc, &K_lds[(w & 1) * 1024]);
            } else {
                const u8* vsrc = qbase + krow + 2 * E_DIM + ch * 16;
                GLOAD_LDS16(vsrc, &V_lds[(w & 1) * 1024]);
            }
        }
        __syncthreads();
        const bool active = (ks0 >= 0) && (ks0 <= qmax) && (ks0 + 31 >= qmin - 128);
        if (active) {
            // ---- S^T = K . Q^T, fp8 MFMA (2 k-tiles x 2 d-chunks) ----
            f32x4 st[2];
            st[0] = 0.f; st[1] = 0.f;
#pragma unroll
            for (int t = 0; t < 2; ++t) {
                const int kk = t * 16 + q;
#pragma unroll
                for (int c = 0; c < 2; ++c) {
                    const long kf = *(const long*)&K_lds[kk * 64 + (((c * 4 + g) ^ (kk & 6)) * 8)];
                    st[t] = __builtin_amdgcn_mfma_f32_16x16x32_fp8_fp8(kf, qfrag[c], st[t], 0, 0, 0);
                }
            }
            // ---- mask + online softmax ----
            float sv[2][4];
            float bm = -3.0e38f;
#pragma unroll
            for (int t = 0; t < 2; ++t)
#pragma unroll
                for (int j = 0; j < 4; ++j) {
                    const int kk = ks0 + t * 16 + 4 * g + j;
                    float x = st[t][j] * 0.125f;
                    const bool ok = (kk <= qs_lane) && (qs_lane - kk <= 128);
                    x = ok ? x : -3.0e38f;
                    sv[t][j] = x;
                    bm = fmaxf(bm, x);
                }
            bm = fmaxf(bm, __shfl_xor(bm, 16));
            bm = fmaxf(bm, __shfl_xor(bm, 32));
            const float mn = fmaxf(m, bm);
            const float sc = __expf(m - mn);
            m = mn;
            float rs = 0.f;
            u32 pw[2];
#pragma unroll
            for (int t = 0; t < 2; ++t) {
                const float e0 = __expf(sv[t][0] - mn), e1 = __expf(sv[t][1] - mn);
                const float e2 = __expf(sv[t][2] - mn), e3 = __expf(sv[t][3] - mn);
                rs += (e0 + e1) + (e2 + e3);
                pw[t] = pk2_fp8(e0, e1) | (pk2_fp8(e2, e3) << 16);   // bytes j=0..3, fp8
            }
            rs += __shfl_xor(rs, 16);
            rs += __shfl_xor(rs, 32);
            l = l * sc + rs;
#pragma unroll
            for (int dt = 0; dt < 4; ++dt) oacc[dt] *= sc;
            // ---- P^T (D-layout, fp8x4 words) -> B-frag (8 fp8 = 2 words) via 4 shuffles ----
            const int src0 = ((2 * g) & 3) * 16 + q;        // k = 8g..8g+3
            const int src1 = ((2 * g + 1) & 3) * 16 + q;    // k = 8g+4..8g+7
            const int w0a = __shfl((int)pw[0], src0), w0b = __shfl((int)pw[1], src0);
            const int w1a = __shfl((int)pw[0], src1), w1b = __shfl((int)pw[1], src1);
            union { u32 u[2]; long l64; } bf;
            bf.u[0] = (u32)((g & 2) ? w0b : w0a);           // t = g>>1 selects word
            bf.u[1] = (u32)((g & 2) ? w1b : w1a);
            // ---- PV: O^T[d][q] += V^T_d . P_q, fp8 MFMA ----
#pragma unroll
            for (int dt = 0; dt < 4; ++dt) {
                union { u8 e8[8]; long l64; } vf;
#pragma unroll
                for (int e = 0; e < 8; ++e)
                    vf.e8[e] = V_lds[(8 * g + e) * 64 + dt * 16 + q];
                oacc[dt] = __builtin_amdgcn_mfma_f32_16x16x32_fp8_fp8(vf.l64, bf.l64, oacc[dt], 0, 0, 0);
            }
        }
        __syncthreads();
    }
    const float inv = 1.f / l;
    u8* obase = o + ((size_t)(b * L_SEQ) + (size_t)qi) * E_DIM + h * HD;
#pragma unroll
    for (int dt = 0; dt < 4; ++dt) {
        const u32 pwo = pk2_fp8(oacc[dt][0] * inv, oacc[dt][1] * inv)
                      | (pk2_fp8(oacc[dt][2] * inv, oacc[dt][3] * inv) << 16);
        *(u32*)(obase + dt * 16 + 4 * g) = pwo;
    }
}

// --------------------------------------------------------------------------------------------
extern "C" void kernel_launch(void* const* d_in, const int* in_sizes, int n_in,
                              void* d_out, int out_size, void* d_ws, size_t ws_size,
                              hipStream_t stream) {
    const float* x    = (const float*)d_in[0];
    const float* ln1g = (const float*)d_in[1];
    const float* ln1b = (const float*)d_in[2];
    const float* qkvw = (const float*)d_in[3];
    const float* qkvb = (const float*)d_in[4];
    const float* outw = (const float*)d_in[5];
    const float* outb = (const float*)d_in[6];
    const float* ln2g = (const float*)d_in[7];
    const float* ln2b = (const float*)d_in[8];
    const float* w1   = (const float*)d_in[9];
    const float* b1   = (const float*)d_in[10];
    const float* w2   = (const float*)d_in[11];
    const float* b2   = (const float*)d_in[12];
    float* outp = (float*)d_out;

    char* ws = (char*)d_ws;
    size_t off = 0;
    auto alloc = [&](size_t bytes) {
        void* p = ws + off;
        off += (bytes + 255) & ~(size_t)255;
        return p;
    };
    u8*    hbuf  = (u8*)   alloc((size_t)BL * E_DIM);
    u8*    qkvB  = (u8*)   alloc((size_t)BL * 3 * E_DIM);
    u8*    obuf  = (u8*)   alloc((size_t)BL * E_DIM);
    u16*   x2    = (u16*)  alloc((size_t)BL * E_DIM * 2);
    u8*    h2    = (u8*)   alloc((size_t)BL * E_DIM);
    u8*    g1    = (u8*)   alloc((size_t)BL * HID_DIM);
    u8*    wqkvT = (u8*)   alloc((size_t)3 * E_DIM * E_DIM);
    u8*    woutT = (u8*)   alloc((size_t)E_DIM * E_DIM);
    u8*    w1T   = (u8*)   alloc((size_t)HID_DIM * E_DIM);
    u8*    w2T   = (u8*)   alloc((size_t)E_DIM * HID_DIM);

    prep<<<BL / 4 + 768, 256, 0, stream>>>(qkvw, outw, w1, w2, wqkvT, woutT, w1T, w2T,
                                           x, ln1g, ln1b, hbuf);
    gemm_f8<E_DIM, 256, 2, 0, false><<<(BL / 128) * 6, 512, 0, stream>>>(
        hbuf, wqkvT, qkvb, nullptr, qkvB, BL, 3 * E_DIM, 6);
    attn_mfma<<<dim3(32, 32), 256, 0, stream>>>(qkvB, obuf);
    gemm_f8<E_DIM, 128, 0, 1, false><<<(BL / 128) * 4, 512, 0, stream>>>(
        obuf, woutT, outb, x, x2, BL, E_DIM, 4);
    ln_b<<<BL / 4, 256, 0, stream>>>(x2, ln2g, ln2b, h2);
    gemm_f8<E_DIM, 256, 2, 0, true><<<(BL / 128) * 8, 512, 0, stream>>>(
        h2, w1T, b1, nullptr, g1, BL, HID_DIM, 8);
    gemm_f8<HID_DIM, 128, 1, 2, false><<<(BL / 128) * 4, 512, 0, stream>>>(
        g1, w2T, b2, x2, outp, BL, E_DIM, 4);
}